// Round 1
// baseline (9737.215 us; speedup 1.0000x reference)
//
#include <hip/hip_runtime.h>

#define B_ 256
#define T_ 256
#define E_ 512
#define V_ 32000
#define NMOV 16

#define CG 12              // column groups (1536 cols / 128)
#define BG 16              // batch groups (256 / 16)
#define NWG (CG*BG)        // 192 workgroups, 1 per CU, co-resident
#define WGT 512            // 8 waves
#define ZSTR 520           // padded bf16 row stride (16B-aligned rows, conflict-light)

#define SQRTE 22.62741699796952f
#define SCALE 0.04419417382415922f   // 1/sqrt(512)

typedef __attribute__((ext_vector_type(8))) short bf16x8;
typedef __attribute__((ext_vector_type(4))) float f32x4;

__device__ __forceinline__ short f2bf(float f) {
  unsigned u = __float_as_uint(f);
  u += 0x7fffu + ((u >> 16) & 1u);          // RNE
  return (short)(u >> 16);
}
__device__ __forceinline__ float bf2f(short s) {
  return __uint_as_float(((unsigned)(unsigned short)s) << 16);
}
__device__ __forceinline__ float wredsum(float v) {
  #pragma unroll
  for (int k = 1; k < 64; k <<= 1) v += __shfl_xor(v, k, 64);
  return v;
}

// ---------------- K1: mover K/V precompute: Km = mover@Wk + bk, Vm = mover@Wv + bv
__global__ void k_movers(const float* __restrict__ Wk, const float* __restrict__ bk,
                         const float* __restrict__ Wv, const float* __restrict__ bv,
                         const float* __restrict__ mover, float* __restrict__ kmvm)
{
  const int m = blockIdx.x & 15;
  const int s = blockIdx.x >> 4;              // 0 -> K, 1 -> V
  const float* W  = s ? Wv : Wk;
  const float* bb = s ? bv : bk;
  const int c = threadIdx.x * 2;
  float a0 = bb[c], a1 = bb[c + 1];
  for (int r = 0; r < E_; ++r) {
    float mv = mover[m * E_ + r];
    float2 wv = *(const float2*)(W + (size_t)r * E_ + c);
    a0 += mv * wv.x; a1 += mv * wv.y;
  }
  kmvm[(s * NMOV + m) * E_ + c]     = a0;
  kmvm[(s * NMOV + m) * E_ + c + 1] = a1;
}

// ---------------- K2: cooperative sequential scan -------------------------
// grid = 192 WGs (16 batch-groups x 12 col-groups), 512 threads (8 waves).
// Each wave: 16 columns of concat [Wq|Wk|Wv], weights register-stationary (bf16).
// Per step: phase A (MFMA z@W -> Y[p]) | grid barrier | phase B (att+LN, redundant
// across the 12 col-groups so no second barrier is needed; Y double-buffered).
__global__ __launch_bounds__(WGT, 2) void k_scan(
    const float* __restrict__ hidden, const int* __restrict__ seq,
    const float* __restrict__ emb,
    const float* __restrict__ Wq, const float* __restrict__ bq,
    const float* __restrict__ Wk, const float* __restrict__ bk,
    const float* __restrict__ Wv, const float* __restrict__ bv,
    const float* __restrict__ gamma, const float* __restrict__ beta,
    const float* __restrict__ kmvm, float* __restrict__ Ybase,
    unsigned* __restrict__ bar, float* __restrict__ zout)
{
  __shared__ __align__(16) short zlds[16][ZSTR];        // z (bf16) for this WG's 16 batches
  __shared__ __align__(16) short kvlds[2][NMOV][E_];    // Km / Vm in bf16

  const int tid = threadIdx.x;
  const int lane = tid & 63;
  const int ww = tid >> 6;
  const int bg = blockIdx.x / CG, cg = blockIdx.x % CG;
  const int row16 = lane & 15;
  const int kq = (lane >> 4) * 8;

  for (int i = tid; i < 2 * NMOV * E_; i += WGT)
    (&kvlds[0][0][0])[i] = f2bf(kmvm[i]);

  // --- register-stationary B fragments: this wave's 16 cols of [Wq|Wk|Wv] ---
  const int c  = cg * 128 + ww * 16 + row16;   // concat col 0..1535
  const int sel = c >> 9;
  const int cc  = c & 511;
  const float* Wm = (sel == 0) ? Wq : ((sel == 1) ? Wk : Wv);
  const float* bm = (sel == 0) ? bq : ((sel == 1) ? bk : bv);
  const float cbias = bm[cc];
  bf16x8 bfrag[16];
  #pragma unroll
  for (int ks = 0; ks < 16; ++ks) {
    #pragma unroll
    for (int j = 0; j < 8; ++j)
      bfrag[ks][j] = f2bf(Wm[(ks * 32 + kq + j) * E_ + cc]);
  }

  // --- per-wave state: 2 batches, z in registers (8 f32/lane/batch) ---
  const int b0 = bg * 16 + ww * 2;
  float zr[2][8], gr[8], br_[8], xn[2][8];
  #pragma unroll
  for (int bi = 0; bi < 2; ++bi) {
    *(float4*)&zr[bi][0] = *(const float4*)(hidden + (size_t)(b0 + bi) * E_ + lane * 8);
    *(float4*)&zr[bi][4] = *(const float4*)(hidden + (size_t)(b0 + bi) * E_ + lane * 8 + 4);
  }
  *(float4*)&gr[0]  = *(const float4*)(gamma + lane * 8);
  *(float4*)&gr[4]  = *(const float4*)(gamma + lane * 8 + 4);
  *(float4*)&br_[0] = *(const float4*)(beta  + lane * 8);
  *(float4*)&br_[4] = *(const float4*)(beta  + lane * 8 + 4);
  #pragma unroll
  for (int bi = 0; bi < 2; ++bi) {
    int idx = seq[(b0 + bi) * T_];
    *(float4*)&xn[bi][0] = *(const float4*)(emb + (size_t)idx * E_ + lane * 8);
    *(float4*)&xn[bi][4] = *(const float4*)(emb + (size_t)idx * E_ + lane * 8 + 4);
  }

  unsigned round = 1;
  int p = 0;

  #pragma unroll 1
  for (int t = 0; t < T_; ++t) {
    // z += x_t ; prefetch x_{t+1}
    #pragma unroll
    for (int bi = 0; bi < 2; ++bi)
      #pragma unroll
      for (int j = 0; j < 8; ++j) zr[bi][j] += xn[bi][j] * SQRTE;
    if (t + 1 < T_) {
      #pragma unroll
      for (int bi = 0; bi < 2; ++bi) {
        int idx = seq[(b0 + bi) * T_ + t + 1];
        *(float4*)&xn[bi][0] = *(const float4*)(emb + (size_t)idx * E_ + lane * 8);
        *(float4*)&xn[bi][4] = *(const float4*)(emb + (size_t)idx * E_ + lane * 8 + 4);
      }
    }
    // stage z (bf16) for MFMA A-operand
    #pragma unroll
    for (int bi = 0; bi < 2; ++bi)
      #pragma unroll
      for (int j = 0; j < 8; ++j)
        zlds[ww * 2 + bi][lane * 8 + j] = f2bf(zr[bi][j]);
    __syncthreads();

    // ---- phase A: 16-batch x 16-col tile, K=512 (16 MFMA) ----
    f32x4 acc = {0.f, 0.f, 0.f, 0.f};
    #pragma unroll
    for (int ks = 0; ks < 16; ++ks) {
      bf16x8 a = *(const bf16x8*)&zlds[row16][ks * 32 + kq];
      acc = __builtin_amdgcn_mfma_f32_16x16x32_bf16(a, bfrag[ks], acc, 0, 0, 0);
    }
    float* Yp = Ybase + (size_t)p * (B_ * 1536);
    #pragma unroll
    for (int r = 0; r < 4; ++r) {
      int row = (lane >> 4) * 4 + r;
      Yp[(size_t)(bg * 16 + row) * 1536 + c] = acc[r] + cbias;
    }

    // ---- grid barrier (1 per step; release/acquire, agent scope) ----
    __syncthreads();                 // drains vmcnt -> all Y stores at L2
    if (tid == 0) {
      __hip_atomic_fetch_add(bar, 1u, __ATOMIC_RELEASE, __HIP_MEMORY_SCOPE_AGENT);
      const unsigned tgt = round * NWG;
      while (__hip_atomic_load(bar, __ATOMIC_ACQUIRE, __HIP_MEMORY_SCOPE_AGENT) < tgt)
        __builtin_amdgcn_s_sleep(2);
    }
    ++round;
    __syncthreads();

    // ---- phase B: attention + LayerNorm (redundant per col-group) ----
    const float* Yrd = Ybase + (size_t)p * (B_ * 1536);
    #pragma unroll
    for (int bi = 0; bi < 2; ++bi) {
      const float* Yr = Yrd + (size_t)(b0 + bi) * 1536;
      float q[8], k0[8], v0[8];
      *(float4*)&q[0]  = *(const float4*)(Yr + lane * 8);
      *(float4*)&q[4]  = *(const float4*)(Yr + lane * 8 + 4);
      *(float4*)&k0[0] = *(const float4*)(Yr + 512 + lane * 8);
      *(float4*)&k0[4] = *(const float4*)(Yr + 512 + lane * 8 + 4);
      *(float4*)&v0[0] = *(const float4*)(Yr + 1024 + lane * 8);
      *(float4*)&v0[4] = *(const float4*)(Yr + 1024 + lane * 8 + 4);

      float dm[16];
      #pragma unroll
      for (int m = 0; m < 16; ++m) {
        bf16x8 km = *(const bf16x8*)(&kvlds[0][m][0] + lane * 8);
        float d = 0.f;
        #pragma unroll
        for (int j = 0; j < 8; ++j) d += q[j] * bf2f(km[j]);
        dm[m] = d;
      }
      float d0 = 0.f;
      #pragma unroll
      for (int j = 0; j < 8; ++j) d0 += q[j] * k0[j];

      float lg[17];
      lg[0] = wredsum(d0) * SCALE;
      #pragma unroll
      for (int m = 0; m < 16; ++m) lg[m + 1] = wredsum(dm[m]) * SCALE;

      float mx = lg[0];
      #pragma unroll
      for (int n = 1; n < 17; ++n) mx = fmaxf(mx, lg[n]);
      float att[17]; float den = 0.f;
      #pragma unroll
      for (int n = 0; n < 17; ++n) { att[n] = __expf(lg[n] - mx); den += att[n]; }
      const float rden = 1.f / den;

      float u[8];
      #pragma unroll
      for (int j = 0; j < 8; ++j) u[j] = att[0] * v0[j];
      #pragma unroll
      for (int m = 0; m < 16; ++m) {
        bf16x8 vm = *(const bf16x8*)(&kvlds[1][m][0] + lane * 8);
        #pragma unroll
        for (int j = 0; j < 8; ++j) u[j] += att[m + 1] * bf2f(vm[j]);
      }
      #pragma unroll
      for (int j = 0; j < 8; ++j) u[j] = zr[bi][j] + u[j] * rden;

      float s1 = 0.f, s2 = 0.f;
      #pragma unroll
      for (int j = 0; j < 8; ++j) { s1 += u[j]; s2 += u[j] * u[j]; }
      s1 = wredsum(s1); s2 = wredsum(s2);
      const float mean = s1 * (1.f / 512.f);
      const float var  = s2 * (1.f / 512.f) - mean * mean;
      const float rstd = rsqrtf(var + 1e-6f);
      #pragma unroll
      for (int j = 0; j < 8; ++j)
        zr[bi][j] = (u[j] - mean) * rstd * gr[j] + br_[j];
    }
    p ^= 1;
  }

  if (cg == 0) {
    #pragma unroll
    for (int bi = 0; bi < 2; ++bi) {
      *(float4*)(zout + (size_t)(b0 + bi) * E_ + lane * 8)     = *(float4*)&zr[bi][0];
      *(float4*)(zout + (size_t)(b0 + bi) * E_ + lane * 8 + 4) = *(float4*)&zr[bi][4];
    }
  }
}

// ---------------- K3: logits = z @ vocab_W + vocab_b (bf16 MFMA) ----------
#define K2_SMEM (128 * ZSTR * 2)

__global__ __launch_bounds__(512, 2) void k_logits(
    const float* __restrict__ z, const float* __restrict__ W,
    const float* __restrict__ bia, float* __restrict__ out)
{
  extern __shared__ short zl[];                 // [128][ZSTR] bf16
  const int tid = threadIdx.x;
  const int btile = blockIdx.x & 1;
  const int vt = blockIdx.x >> 1;
  for (int i = tid; i < 128 * 128; i += 512) {
    int row = i >> 7, c4 = (i & 127) << 2;
    float4 zv = *(const float4*)(z + (size_t)(btile * 128 + row) * E_ + c4);
    short* d = zl + row * ZSTR + c4;
    d[0] = f2bf(zv.x); d[1] = f2bf(zv.y); d[2] = f2bf(zv.z); d[3] = f2bf(zv.w);
  }
  __syncthreads();
  const int lane = tid & 63, w = tid >> 6;
  const int vc = vt * 128 + w * 16 + (lane & 15);
  const int kq = (lane >> 4) * 8;
  f32x4 acc[8];
  #pragma unroll
  for (int rt = 0; rt < 8; ++rt) acc[rt] = (f32x4){0.f, 0.f, 0.f, 0.f};
  for (int ks = 0; ks < 16; ++ks) {
    bf16x8 bf;
    #pragma unroll
    for (int j = 0; j < 8; ++j)
      bf[j] = f2bf(W[(size_t)(ks * 32 + kq + j) * V_ + vc]);
    #pragma unroll
    for (int rt = 0; rt < 8; ++rt) {
      bf16x8 a = *(const bf16x8*)&zl[(rt * 16 + (lane & 15)) * ZSTR + ks * 32 + kq];
      acc[rt] = __builtin_amdgcn_mfma_f32_16x16x32_bf16(a, bf, acc[rt], 0, 0, 0);
    }
  }
  const float bb = bia[vc];
  #pragma unroll
  for (int rt = 0; rt < 8; ++rt)
    #pragma unroll
    for (int r = 0; r < 4; ++r)
      out[(size_t)(btile * 128 + rt * 16 + (lane >> 4) * 4 + r) * V_ + vc] = acc[rt][r] + bb;
}

// ---------------- K4: in-place log_softmax over vocab ---------------------
__global__ void k_logsoftmax(float* __restrict__ y)
{
  float* L = y + (size_t)blockIdx.x * V_;
  float m = -3.402823466e+38f, s = 0.f;
  for (int i = threadIdx.x; i < V_; i += 256) {
    float l = L[i];
    if (l > m) { s = s * __expf(m - l) + 1.f; m = l; }
    else       { s += __expf(l - m); }
  }
  #pragma unroll
  for (int k = 1; k < 64; k <<= 1) {
    float m2 = __shfl_xor(m, k, 64);
    float s2 = __shfl_xor(s, k, 64);
    float M = fmaxf(m, m2);
    s = s * __expf(m - M) + s2 * __expf(m2 - M);
    m = M;
  }
  __shared__ float ms[4], ss[4];
  if ((threadIdx.x & 63) == 0) { ms[threadIdx.x >> 6] = m; ss[threadIdx.x >> 6] = s; }
  __syncthreads();
  float M = fmaxf(fmaxf(ms[0], ms[1]), fmaxf(ms[2], ms[3]));
  float S = ss[0] * __expf(ms[0] - M) + ss[1] * __expf(ms[1] - M) +
            ss[2] * __expf(ms[2] - M) + ss[3] * __expf(ms[3] - M);
  const float lse = M + logf(S);
  for (int i = threadIdx.x; i < V_; i += 256) L[i] -= lse;
}

extern "C" void kernel_launch(void* const* d_in, const int* in_sizes, int n_in,
                              void* d_out, int out_size, void* d_ws, size_t ws_size,
                              hipStream_t stream) {
  const float* hidden = (const float*)d_in[0];
  const int*   seq    = (const int*)  d_in[1];
  const float* emb    = (const float*)d_in[2];
  const float* Wq     = (const float*)d_in[3];
  const float* bq     = (const float*)d_in[4];
  const float* Wk     = (const float*)d_in[5];
  const float* bk     = (const float*)d_in[6];
  const float* Wv     = (const float*)d_in[7];
  const float* bv     = (const float*)d_in[8];
  const float* mover  = (const float*)d_in[9];
  const float* gamma  = (const float*)d_in[10];
  const float* beta   = (const float*)d_in[11];
  const float* vocabW = (const float*)d_in[12];
  const float* vocabB = (const float*)d_in[13];

  float* zout = (float*)d_out;                  // (256,1,512)
  float* yout = zout + (size_t)B_ * E_;         // (256,1,32000); also Y scan scratch
  unsigned* bar = (unsigned*)d_ws;
  float* kmvm = (float*)((char*)d_ws + 256);    // [2][16][512] f32
  float* Ybase = yout;                          // 2*256*1536 floats, overwritten by k_logits

  hipMemsetAsync(bar, 0, 256, stream);
  hipLaunchKernelGGL(k_movers, dim3(32), dim3(256), 0, stream, Wk, bk, Wv, bv, mover, kmvm);

  void* args[] = {(void*)&hidden, (void*)&seq, (void*)&emb,
                  (void*)&Wq, (void*)&bq, (void*)&Wk, (void*)&bk, (void*)&Wv, (void*)&bv,
                  (void*)&gamma, (void*)&beta, (void*)&kmvm, (void*)&Ybase,
                  (void*)&bar, (void*)&zout};
  hipLaunchCooperativeKernel((const void*)k_scan, dim3(NWG), dim3(WGT), args, 0, stream);

  hipFuncSetAttribute((const void*)k_logits, hipFuncAttributeMaxDynamicSharedMemorySize, K2_SMEM);
  hipLaunchKernelGGL(k_logits, dim3(500), dim3(512), K2_SMEM, stream, zout, vocabW, vocabB, yout);
  hipLaunchKernelGGL(k_logsoftmax, dim3(256), dim3(256), 0, stream, yout);
}

// Round 2
// 9162.875 us; speedup vs baseline: 1.0627x; 1.0627x over previous
//
#include <hip/hip_runtime.h>

#define B_ 256
#define T_ 256
#define E_ 512
#define V_ 32000
#define NMOV 16
#define NT 65              // column tiles: A(32) | Wv(32) | Wqk(1)
#define STRW 1184          // Ybf LDS row stride (bf16 units)
#define ZSTR 520           // k_logits LDS stride

#define SQRTE 22.62741699796952f
#define SCALE 0.04419417382415922f   // 1/sqrt(512)

typedef __attribute__((ext_vector_type(8))) short bf16x8;
typedef __attribute__((ext_vector_type(4))) short bf16x4;
typedef __attribute__((ext_vector_type(4))) float f32x4;

__device__ __forceinline__ short f2bf(float f) {
  unsigned u = __float_as_uint(f);
  u += 0x7fffu + ((u >> 16) & 1u);          // RNE
  return (short)(u >> 16);
}
__device__ __forceinline__ float bf2f(short s) {
  return __uint_as_float(((unsigned)(unsigned short)s) << 16);
}
__device__ __forceinline__ float wredsum(float v) {
  #pragma unroll
  for (int k = 1; k < 64; k <<= 1) v += __shfl_xor(v, k, 64);
  return v;
}

// ---------------- K1: mover K/V: Km = mover@Wk + bk, Vm = mover@Wv + bv ----
__global__ void k_movers(const float* __restrict__ Wk, const float* __restrict__ bk,
                         const float* __restrict__ Wv, const float* __restrict__ bv,
                         const float* __restrict__ mover, float* __restrict__ kmvm)
{
  const int m = blockIdx.x & 15;
  const int s = blockIdx.x >> 4;              // 0 -> K, 1 -> V
  const float* W  = s ? Wv : Wk;
  const float* bb = s ? bv : bk;
  const int c = threadIdx.x * 2;
  float a0 = bb[c], a1 = bb[c + 1];
  for (int r = 0; r < E_; ++r) {
    float mv = mover[m * E_ + r];
    float2 wv = *(const float2*)(W + (size_t)r * E_ + c);
    a0 += mv * wv.x; a1 += mv * wv.y;
  }
  kmvm[(s * NMOV + m) * E_ + c]     = a0;
  kmvm[(s * NMOV + m) * E_ + c + 1] = a1;
}

// ---------------- K2: A = Wq @ Wk^T (bf16 MFMA, f32 out) -------------------
__global__ void k_gemmA(const float* __restrict__ Wq, const float* __restrict__ Wk,
                        float* __restrict__ A)
{
  const int ti = blockIdx.x >> 5, tj = blockIdx.x & 31;
  const int l = threadIdx.x, r16 = l & 15, kq = (l >> 4) * 8;
  f32x4 acc = {0.f, 0.f, 0.f, 0.f};
  for (int ks = 0; ks < 16; ++ks) {
    const float* ap = Wq + (size_t)(ti * 16 + r16) * E_ + ks * 32 + kq;
    const float* bp = Wk + (size_t)(tj * 16 + r16) * E_ + ks * 32 + kq;
    bf16x8 a, b;
    #pragma unroll
    for (int j = 0; j < 8; ++j) { a[j] = f2bf(ap[j]); b[j] = f2bf(bp[j]); }
    acc = __builtin_amdgcn_mfma_f32_16x16x32_bf16(a, b, acc, 0, 0, 0);
  }
  #pragma unroll
  for (int r = 0; r < 4; ++r)
    A[(size_t)(ti * 16 + (l >> 4) * 4 + r) * E_ + tj * 16 + r16] = acc[r];
}

// ---------------- K3: Wqk[i][m] = sum_j Wq[i][j] * Km[m][j] ----------------
__global__ void k_wqk(const float* __restrict__ Wq, const float* __restrict__ kmvm,
                      float* __restrict__ Wqk)
{
  const int i = blockIdx.x;
  const int l = threadIdx.x, m = l & 15, sl = l >> 4;
  float p = 0.f;
  for (int j = sl * 128; j < sl * 128 + 128; ++j)
    p += Wq[(size_t)i * E_ + j] * kmvm[(size_t)m * E_ + j];
  p += __shfl_xor(p, 16, 64);
  p += __shfl_xor(p, 32, 64);
  if (l < 16) Wqk[i * 16 + m] = p;
}

// ---------------- K4: cvec[i] = Wq[i]·bk + Wk[i]·bq ------------------------
__global__ void k_cvec(const float* __restrict__ Wq, const float* __restrict__ Wk,
                       const float* __restrict__ bq, const float* __restrict__ bk,
                       float* __restrict__ cvec)
{
  const int i = blockIdx.x * 64 + threadIdx.x;
  float s = 0.f;
  for (int j = 0; j < E_; ++j)
    s += Wq[(size_t)i * E_ + j] * bk[j] + Wk[(size_t)i * E_ + j] * bq[j];
  cvec[i] = s;
}

// ---------------- K5: lb[m] = bq·Km[m] (m<16), lb[16] = bq·bk --------------
__global__ void k_lb(const float* __restrict__ bq, const float* __restrict__ bk,
                     const float* __restrict__ kmvm, float* __restrict__ lb)
{
  const int l = threadIdx.x;
  if (l < 16) {
    float s = 0.f;
    for (int j = 0; j < E_; ++j) s += bq[j] * kmvm[(size_t)l * E_ + j];
    lb[l] = s;
  } else if (l == 16) {
    float s = 0.f;
    for (int j = 0; j < E_; ++j) s += bq[j] * bk[j];
    lb[16] = s;
  }
}

// ---------------- K6: pack Wcat = [A | Wv | Wqk] into MFMA fragment order --
// Wfrag[(ct*16+ks)*64 + lane][0..7] = Wcat[ks*32 + (lane>>4)*8 + j][ct*16 + (lane&15)]
__global__ void k_pack(const float* __restrict__ A, const float* __restrict__ Wv,
                       const float* __restrict__ Wqk, short* __restrict__ Wfrag)
{
  const int blk = blockIdx.x;          // ct*16 + ks
  const int ct = blk >> 4, ks = blk & 15;
  const int l = threadIdx.x;
  const int c = ct * 16 + (l & 15);
  const int r0 = ks * 32 + (l >> 4) * 8;
  short v[8];
  #pragma unroll
  for (int j = 0; j < 8; ++j) {
    const int r = r0 + j;
    float x;
    if (c < 512)       x = A[(size_t)r * E_ + c];
    else if (c < 1024) x = Wv[(size_t)r * E_ + (c - 512)];
    else               x = Wqk[r * 16 + (c - 1024)];
    v[j] = f2bf(x);
  }
  *(bf16x8*)(Wfrag + ((size_t)blk * 64 + l) * 8) = *(const bf16x8*)v;
}

// ---------------- K7: independent per-WG sequential scan -------------------
// 16 WGs x 512 threads; WG owns 16 batches; weights stream L2->VGPR per step.
// Y = z @ [A|Wv|Wqk]; transposed-output MFMA (C[col][batch]) so Y->LDS is b64.
__global__ __launch_bounds__(512, 2) void k_scan2(
    const float* __restrict__ hidden, const int* __restrict__ seq,
    const float* __restrict__ emb,
    const float* __restrict__ gamma, const float* __restrict__ beta,
    const float* __restrict__ bv,
    const float* __restrict__ kmvm, const float* __restrict__ cvec,
    const float* __restrict__ lb, const short* __restrict__ Wfrag,
    float* __restrict__ zout)
{
  __shared__ __align__(16) short zf[16 * 64 * 8];     // z fragments (bf16), XOR-swizzled
  __shared__ __align__(16) short Ybf[16][STRW];       // Y (bf16), col-XOR-swizzled
  __shared__ __align__(16) short vml[NMOV][E_];       // Vm (bf16)
  __shared__ float bvl[E_], cl[E_], gl[E_], bl[E_], lbl[20];

  const int tid = threadIdx.x, l = tid & 63, ww = tid >> 6;
  const int wg = blockIdx.x;

  // stage constants
  for (int i = tid; i < NMOV * E_; i += 512)
    (&vml[0][0])[i] = f2bf(kmvm[NMOV * E_ + i]);      // Vm = kmvm[1]
  for (int i = tid; i < E_; i += 512) {
    bvl[i] = bv[i]; cl[i] = cvec[i]; gl[i] = gamma[i]; bl[i] = beta[i];
  }
  if (tid < 17) lbl[tid] = lb[tid];

  // per-wave state: 2 batches, z in registers (8 f32/lane/batch)
  const int b0 = wg * 16 + ww * 2;
  float zr[2][8], xn[2][8];
  #pragma unroll
  for (int bi = 0; bi < 2; ++bi) {
    *(float4*)&zr[bi][0] = *(const float4*)(hidden + (size_t)(b0 + bi) * E_ + l * 8);
    *(float4*)&zr[bi][4] = *(const float4*)(hidden + (size_t)(b0 + bi) * E_ + l * 8 + 4);
    int idx = seq[(b0 + bi) * T_];
    *(float4*)&xn[bi][0] = *(const float4*)(emb + (size_t)idx * E_ + l * 8);
    *(float4*)&xn[bi][4] = *(const float4*)(emb + (size_t)idx * E_ + l * 8 + 4);
  }
  __syncthreads();

  #pragma unroll 1
  for (int t = 0; t < T_; ++t) {
    // z += x_t * sqrt(E); stage z fragments; prefetch x_{t+1}
    #pragma unroll
    for (int bi = 0; bi < 2; ++bi) {
      #pragma unroll
      for (int j = 0; j < 8; ++j) zr[bi][j] += xn[bi][j] * SQRTE;
      short tmp[8];
      #pragma unroll
      for (int j = 0; j < 8; ++j) tmp[j] = f2bf(zr[bi][j]);
      const int ks = l >> 2;
      const int u  = ((l & 3) << 4) | (ww * 2 + bi);
      *(bf16x8*)&zf[((ks << 6) + (u ^ (ks & 7))) * 8] = *(const bf16x8*)tmp;
    }
    if (t + 1 < T_) {
      #pragma unroll
      for (int bi = 0; bi < 2; ++bi) {
        int idx = seq[(b0 + bi) * T_ + t + 1];
        *(float4*)&xn[bi][0] = *(const float4*)(emb + (size_t)idx * E_ + l * 8);
        *(float4*)&xn[bi][4] = *(const float4*)(emb + (size_t)idx * E_ + l * 8 + 4);
      }
    }
    __syncthreads();

    // ---- GEMM: per wave 8 tiles (+tile 64 on wave 0), 2 K-half passes ----
    f32x4 acc[8]; f32x4 acc9 = {0.f, 0.f, 0.f, 0.f};
    #pragma unroll
    for (int i = 0; i < 8; ++i) acc[i] = (f32x4){0.f, 0.f, 0.f, 0.f};

    #pragma unroll
    for (int kh = 0; kh < 2; ++kh) {
      bf16x8 zb[8];
      #pragma unroll
      for (int k8 = 0; k8 < 8; ++k8) {
        const int ks = kh * 8 + k8;
        zb[k8] = *(const bf16x8*)&zf[((ks << 6) + (l ^ (ks & 7))) * 8];
      }
      bf16x8 bufs[3][8];
      #define LOADH(BUF, CT) do { \
        const short* _p = Wfrag + (((size_t)(CT) * 16 + kh * 8) * 64 + l) * 8; \
        _Pragma("unroll") \
        for (int _k = 0; _k < 8; ++_k) BUF[_k] = *(const bf16x8*)(_p + (size_t)_k * 512); \
      } while (0)
      LOADH(bufs[0], ww);
      LOADH(bufs[1], ww + 8);
      #pragma unroll
      for (int ti = 0; ti < 9; ++ti) {
        if (ti + 2 < 8) {
          LOADH(bufs[(ti + 2) % 3], ww + (ti + 2) * 8);
        } else if (ti + 2 == 8) {
          if (ww == 0) LOADH(bufs[2], 64);
        }
        if (ti < 8) {
          #pragma unroll
          for (int k8 = 0; k8 < 8; ++k8)
            acc[ti] = __builtin_amdgcn_mfma_f32_16x16x32_bf16(bufs[ti % 3][k8], zb[k8], acc[ti], 0, 0, 0);
        } else if (ww == 0) {
          #pragma unroll
          for (int k8 = 0; k8 < 8; ++k8)
            acc9 = __builtin_amdgcn_mfma_f32_16x16x32_bf16(bufs[2][k8], zb[k8], acc9, 0, 0, 0);
        }
      }
      #undef LOADH
    }

    // store Y -> LDS (bf16, col-swizzled); acc[r] = Y[batch=l&15][ct*16+(l>>4)*4+r]
    {
      const int bat = l & 15;
      const int csw = (bat & 7) << 3;
      #pragma unroll
      for (int ti = 0; ti < 8; ++ti) {
        const int colb = (ww + ti * 8) * 16 + ((l >> 4) << 2);
        bf16x4 o;
        #pragma unroll
        for (int r = 0; r < 4; ++r) o[r] = f2bf(acc[ti][r]);
        *(bf16x4*)&Ybf[bat][colb ^ csw] = o;
      }
      if (ww == 0) {
        const int colb = 1024 + ((l >> 4) << 2);
        bf16x4 o;
        #pragma unroll
        for (int r = 0; r < 4; ++r) o[r] = f2bf(acc9[r]);
        *(bf16x4*)&Ybf[bat][colb ^ csw] = o;
      }
    }
    __syncthreads();

    // ---- phase B: logits / softmax / PV / LayerNorm (2 batches per wave) --
    #pragma unroll
    for (int bi = 0; bi < 2; ++bi) {
      const int bloc = ww * 2 + bi;
      const int swz = (bloc & 7) << 3;
      const bf16x8 wv = *(const bf16x8*)&Ybf[bloc][(l * 8) ^ swz];
      const bf16x8 vv = *(const bf16x8*)&Ybf[bloc][(512 + l * 8) ^ swz];
      float cw[8], bw[8], gw[8], bb[8];
      *(float4*)&cw[0] = *(const float4*)&cl[l * 8];
      *(float4*)&cw[4] = *(const float4*)&cl[l * 8 + 4];
      *(float4*)&bw[0] = *(const float4*)&bvl[l * 8];
      *(float4*)&bw[4] = *(const float4*)&bvl[l * 8 + 4];

      float part = 0.f;
      #pragma unroll
      for (int j = 0; j < 8; ++j) part += (bf2f(wv[j]) + cw[j]) * zr[bi][j];

      float lgt[17];
      lgt[0] = (wredsum(part) + lbl[16]) * SCALE;
      #pragma unroll
      for (int m = 0; m < 16; ++m)
        lgt[m + 1] = (bf2f(Ybf[bloc][(1024 + m) ^ swz]) + lbl[m]) * SCALE;

      float mx = lgt[0];
      #pragma unroll
      for (int n = 1; n < 17; ++n) mx = fmaxf(mx, lgt[n]);
      float att[17], den = 0.f;
      #pragma unroll
      for (int n = 0; n < 17; ++n) { att[n] = __expf(lgt[n] - mx); den += att[n]; }
      const float rden = 1.f / den;

      float u[8];
      #pragma unroll
      for (int j = 0; j < 8; ++j) u[j] = att[0] * (bf2f(vv[j]) + bw[j]);
      #pragma unroll
      for (int m = 0; m < 16; ++m) {
        const bf16x8 vm = *(const bf16x8*)&vml[m][l * 8];
        #pragma unroll
        for (int j = 0; j < 8; ++j) u[j] += att[m + 1] * bf2f(vm[j]);
      }
      #pragma unroll
      for (int j = 0; j < 8; ++j) u[j] = zr[bi][j] + u[j] * rden;

      float s1 = 0.f, s2 = 0.f;
      #pragma unroll
      for (int j = 0; j < 8; ++j) { s1 += u[j]; s2 += u[j] * u[j]; }
      s1 = wredsum(s1); s2 = wredsum(s2);
      const float mean = s1 * (1.f / 512.f);
      const float var  = s2 * (1.f / 512.f) - mean * mean;
      const float rstd = rsqrtf(var + 1e-6f);
      *(float4*)&gw[0] = *(const float4*)&gl[l * 8];
      *(float4*)&gw[4] = *(const float4*)&gl[l * 8 + 4];
      *(float4*)&bb[0] = *(const float4*)&bl[l * 8];
      *(float4*)&bb[4] = *(const float4*)&bl[l * 8 + 4];
      #pragma unroll
      for (int j = 0; j < 8; ++j)
        zr[bi][j] = (u[j] - mean) * rstd * gw[j] + bb[j];
    }
  }

  #pragma unroll
  for (int bi = 0; bi < 2; ++bi) {
    *(float4*)(zout + (size_t)(b0 + bi) * E_ + l * 8)     = *(float4*)&zr[bi][0];
    *(float4*)(zout + (size_t)(b0 + bi) * E_ + l * 8 + 4) = *(float4*)&zr[bi][4];
  }
}

// ---------------- K8: logits = z @ vocab_W + vocab_b (bf16 MFMA) -----------
#define K2_SMEM (128 * ZSTR * 2)

__global__ __launch_bounds__(512, 2) void k_logits(
    const float* __restrict__ z, const float* __restrict__ W,
    const float* __restrict__ bia, float* __restrict__ out)
{
  extern __shared__ short zl[];                 // [128][ZSTR] bf16
  const int tid = threadIdx.x;
  const int btile = blockIdx.x & 1;
  const int vt = blockIdx.x >> 1;
  for (int i = tid; i < 128 * 128; i += 512) {
    int row = i >> 7, c4 = (i & 127) << 2;
    float4 zv = *(const float4*)(z + (size_t)(btile * 128 + row) * E_ + c4);
    short* d = zl + row * ZSTR + c4;
    d[0] = f2bf(zv.x); d[1] = f2bf(zv.y); d[2] = f2bf(zv.z); d[3] = f2bf(zv.w);
  }
  __syncthreads();
  const int lane = tid & 63, w = tid >> 6;
  const int vc = vt * 128 + w * 16 + (lane & 15);
  const int kq = (lane >> 4) * 8;
  f32x4 acc[8];
  #pragma unroll
  for (int rt = 0; rt < 8; ++rt) acc[rt] = (f32x4){0.f, 0.f, 0.f, 0.f};
  for (int ks = 0; ks < 16; ++ks) {
    bf16x8 bf;
    #pragma unroll
    for (int j = 0; j < 8; ++j)
      bf[j] = f2bf(W[(size_t)(ks * 32 + kq + j) * V_ + vc]);
    #pragma unroll
    for (int rt = 0; rt < 8; ++rt) {
      bf16x8 a = *(const bf16x8*)&zl[(rt * 16 + (lane & 15)) * ZSTR + ks * 32 + kq];
      acc[rt] = __builtin_amdgcn_mfma_f32_16x16x32_bf16(a, bf, acc[rt], 0, 0, 0);
    }
  }
  const float bb = bia[vc];
  #pragma unroll
  for (int rt = 0; rt < 8; ++rt)
    #pragma unroll
    for (int r = 0; r < 4; ++r)
      out[(size_t)(btile * 128 + rt * 16 + (lane >> 4) * 4 + r) * V_ + vc] = acc[rt][r] + bb;
}

// ---------------- K9: in-place log_softmax over vocab ----------------------
__global__ void k_logsoftmax(float* __restrict__ y)
{
  float* L = y + (size_t)blockIdx.x * V_;
  float m = -3.402823466e+38f, s = 0.f;
  for (int i = threadIdx.x; i < V_; i += 256) {
    float l = L[i];
    if (l > m) { s = s * __expf(m - l) + 1.f; m = l; }
    else       { s += __expf(l - m); }
  }
  #pragma unroll
  for (int k = 1; k < 64; k <<= 1) {
    float m2 = __shfl_xor(m, k, 64);
    float s2 = __shfl_xor(s, k, 64);
    float M = fmaxf(m, m2);
    s = s * __expf(m - M) + s2 * __expf(m2 - M);
    m = M;
  }
  __shared__ float ms[4], ss[4];
  if ((threadIdx.x & 63) == 0) { ms[threadIdx.x >> 6] = m; ss[threadIdx.x >> 6] = s; }
  __syncthreads();
  float M = fmaxf(fmaxf(ms[0], ms[1]), fmaxf(ms[2], ms[3]));
  float S = ss[0] * __expf(ms[0] - M) + ss[1] * __expf(ms[1] - M) +
            ss[2] * __expf(ms[2] - M) + ss[3] * __expf(ms[3] - M);
  const float lse = M + logf(S);
  for (int i = threadIdx.x; i < V_; i += 256) L[i] -= lse;
}

extern "C" void kernel_launch(void* const* d_in, const int* in_sizes, int n_in,
                              void* d_out, int out_size, void* d_ws, size_t ws_size,
                              hipStream_t stream) {
  const float* hidden = (const float*)d_in[0];
  const int*   seq    = (const int*)  d_in[1];
  const float* emb    = (const float*)d_in[2];
  const float* Wq     = (const float*)d_in[3];
  const float* bq     = (const float*)d_in[4];
  const float* Wk     = (const float*)d_in[5];
  const float* bk     = (const float*)d_in[6];
  const float* Wv     = (const float*)d_in[7];
  const float* bv     = (const float*)d_in[8];
  const float* mover  = (const float*)d_in[9];
  const float* gamma  = (const float*)d_in[10];
  const float* beta   = (const float*)d_in[11];
  const float* vocabW = (const float*)d_in[12];
  const float* vocabB = (const float*)d_in[13];

  float* zoutp = (float*)d_out;                 // (256,1,512)
  float* yout  = zoutp + (size_t)B_ * E_;       // (256,1,32000); scratch until k_logits

  // scratch inside yout (overwritten by k_logits afterwards)
  short* Wfrag = (short*)yout;                  // 65*16*64*8 = 532480 bf16
  float* A     = yout + 266240;                 // 512*512
  float* Wqk   = A + 262144;                    // 512*16
  float* cvec  = Wqk + 8192;                    // 512
  float* lbp   = cvec + 512;                    // 17 (pad 32)
  float* kmvmS = lbp + 32;                      // 2*16*512

  hipLaunchKernelGGL(k_movers, dim3(32), dim3(256), 0, stream, Wk, bk, Wv, bv, mover, kmvmS);
  hipLaunchKernelGGL(k_gemmA,  dim3(1024), dim3(64), 0, stream, Wq, Wk, A);
  hipLaunchKernelGGL(k_wqk,    dim3(512), dim3(64), 0, stream, Wq, kmvmS, Wqk);
  hipLaunchKernelGGL(k_cvec,   dim3(8), dim3(64), 0, stream, Wq, Wk, bq, bk, cvec);
  hipLaunchKernelGGL(k_lb,     dim3(1), dim3(64), 0, stream, bq, bk, kmvmS, lbp);
  hipLaunchKernelGGL(k_pack,   dim3(NT * 16), dim3(64), 0, stream, A, Wv, Wqk, Wfrag);

  hipLaunchKernelGGL(k_scan2, dim3(16), dim3(512), 0, stream,
                     hidden, seq, emb, gamma, beta, bv, kmvmS, cvec, lbp, Wfrag, zoutp);

  hipFuncSetAttribute((const void*)k_logits, hipFuncAttributeMaxDynamicSharedMemorySize, K2_SMEM);
  hipLaunchKernelGGL(k_logits, dim3(500), dim3(512), K2_SMEM, stream, zoutp, vocabW, vocabB, yout);
  hipLaunchKernelGGL(k_logsoftmax, dim3(256), dim3(256), 0, stream, yout);
}

// Round 3
// 4053.075 us; speedup vs baseline: 2.4024x; 2.2607x over previous
//
#include <hip/hip_runtime.h>

#define B_ 256
#define T_ 256
#define E_ 512
#define V_ 32000
#define NMOV 16
#define NT 65              // column tiles: A(32) | Wv(32) | Wqk(1)
#define NCG 16             // column groups
#define NBG 16             // batch groups
#define YSTR 1056          // Y exchange row stride (bf16 units)
#define ZSTR 520           // k_logits LDS stride

#define SQRTE 22.62741699796952f
#define SCALE 0.04419417382415922f   // 1/sqrt(512)

typedef __attribute__((ext_vector_type(8))) short bf16x8;
typedef __attribute__((ext_vector_type(4))) short bf16x4;
typedef __attribute__((ext_vector_type(4))) float f32x4;

__device__ __forceinline__ short f2bf(float f) {
  unsigned u = __float_as_uint(f);
  u += 0x7fffu + ((u >> 16) & 1u);          // RNE
  return (short)(u >> 16);
}
__device__ __forceinline__ float bf2f(short s) {
  return __uint_as_float(((unsigned)(unsigned short)s) << 16);
}
__device__ __forceinline__ float wredsum(float v) {
  #pragma unroll
  for (int k = 1; k < 64; k <<= 1) v += __shfl_xor(v, k, 64);
  return v;
}

// ---------------- K1: mover K/V: Km = mover@Wk + bk, Vm = mover@Wv + bv ----
__global__ void k_movers(const float* __restrict__ Wk, const float* __restrict__ bk,
                         const float* __restrict__ Wv, const float* __restrict__ bv,
                         const float* __restrict__ mover, float* __restrict__ kmvm)
{
  const int m = blockIdx.x & 15;
  const int s = blockIdx.x >> 4;              // 0 -> K, 1 -> V
  const float* W  = s ? Wv : Wk;
  const float* bb = s ? bv : bk;
  const int c = threadIdx.x * 2;
  float a0 = bb[c], a1 = bb[c + 1];
  for (int r = 0; r < E_; ++r) {
    float mv = mover[m * E_ + r];
    float2 wv = *(const float2*)(W + (size_t)r * E_ + c);
    a0 += mv * wv.x; a1 += mv * wv.y;
  }
  kmvm[(s * NMOV + m) * E_ + c]     = a0;
  kmvm[(s * NMOV + m) * E_ + c + 1] = a1;
}

// ---------------- K2: A = Wq @ Wk^T (bf16 MFMA, f32 out) -------------------
__global__ void k_gemmA(const float* __restrict__ Wq, const float* __restrict__ Wk,
                        float* __restrict__ A)
{
  const int ti = blockIdx.x >> 5, tj = blockIdx.x & 31;
  const int l = threadIdx.x, r16 = l & 15, kq = (l >> 4) * 8;
  f32x4 acc = {0.f, 0.f, 0.f, 0.f};
  for (int ks = 0; ks < 16; ++ks) {
    const float* ap = Wq + (size_t)(ti * 16 + r16) * E_ + ks * 32 + kq;
    const float* bp = Wk + (size_t)(tj * 16 + r16) * E_ + ks * 32 + kq;
    bf16x8 a, b;
    #pragma unroll
    for (int j = 0; j < 8; ++j) { a[j] = f2bf(ap[j]); b[j] = f2bf(bp[j]); }
    acc = __builtin_amdgcn_mfma_f32_16x16x32_bf16(a, b, acc, 0, 0, 0);
  }
  #pragma unroll
  for (int r = 0; r < 4; ++r)
    A[(size_t)(ti * 16 + (l >> 4) * 4 + r) * E_ + tj * 16 + r16] = acc[r];
}

// ---------------- K3: Wqk[i][m] = sum_j Wq[i][j] * Km[m][j] ----------------
__global__ void k_wqk(const float* __restrict__ Wq, const float* __restrict__ kmvm,
                      float* __restrict__ Wqk)
{
  const int i = blockIdx.x;
  const int l = threadIdx.x, m = l & 15, sl = l >> 4;
  float p = 0.f;
  for (int j = sl * 128; j < sl * 128 + 128; ++j)
    p += Wq[(size_t)i * E_ + j] * kmvm[(size_t)m * E_ + j];
  p += __shfl_xor(p, 16, 64);
  p += __shfl_xor(p, 32, 64);
  if (l < 16) Wqk[i * 16 + m] = p;
}

// ---------------- K4: cvec[i] = Wq[i]·bk + Wk[i]·bq ------------------------
__global__ void k_cvec(const float* __restrict__ Wq, const float* __restrict__ Wk,
                       const float* __restrict__ bq, const float* __restrict__ bk,
                       float* __restrict__ cvec)
{
  const int i = blockIdx.x * 64 + threadIdx.x;
  float s = 0.f;
  for (int j = 0; j < E_; ++j)
    s += Wq[(size_t)i * E_ + j] * bk[j] + Wk[(size_t)i * E_ + j] * bq[j];
  cvec[i] = s;
}

// ---------------- K5: lb[m] = bq·Km[m] (m<16), lb[16] = bq·bk --------------
__global__ void k_lb(const float* __restrict__ bq, const float* __restrict__ bk,
                     const float* __restrict__ kmvm, float* __restrict__ lb)
{
  const int l = threadIdx.x;
  if (l < 16) {
    float s = 0.f;
    for (int j = 0; j < E_; ++j) s += bq[j] * kmvm[(size_t)l * E_ + j];
    lb[l] = s;
  } else if (l == 16) {
    float s = 0.f;
    for (int j = 0; j < E_; ++j) s += bq[j] * bk[j];
    lb[16] = s;
  }
}

// ---------------- K6: pack Wcat = [A | Wv | Wqk] into MFMA fragment order --
// Wfrag[(ct*16+ks)*64 + lane][0..7] = Wcat[ks*32 + (lane>>4)*8 + j][ct*16 + (lane&15)]
__global__ void k_pack(const float* __restrict__ A, const float* __restrict__ Wv,
                       const float* __restrict__ Wqk, short* __restrict__ Wfrag)
{
  const int blk = blockIdx.x;          // ct*16 + ks
  const int ct = blk >> 4, ks = blk & 15;
  const int l = threadIdx.x;
  const int c = ct * 16 + (l & 15);
  const int r0 = ks * 32 + (l >> 4) * 8;
  short v[8];
  #pragma unroll
  for (int j = 0; j < 8; ++j) {
    const int r = r0 + j;
    float x;
    if (c < 512)       x = A[(size_t)r * E_ + c];
    else if (c < 1024) x = Wv[(size_t)r * E_ + (c - 512)];
    else               x = Wqk[r * 16 + (c - 1024)];
    v[j] = f2bf(x);
  }
  *(bf16x8*)(Wfrag + ((size_t)blk * 64 + l) * 8) = *(const bf16x8*)v;
}

// ---------------- K7: LDS-resident partitioned scan ------------------------
// 256 WGs = 16 col-groups x 16 batch-groups, 512 threads (8 waves), 1 WG/CU.
// WG(cg,bg): holds tiles [cg*4, cg*4+ntiles) in LDS for the whole scan.
// Per step: waves 0-3(+4) MFMA z@Wslice -> Y[p] (global bf16); wave 7 publishes
// x_{t+1}; release+inc bar[bg]; spin until all 16 cgs arrive; phase B
// (softmax+PV+LN) recomputed redundantly per cg from Y[p]. One sync per step.
__global__ __launch_bounds__(512, 2) void k_scan3(
    const float* __restrict__ hidden, const int* __restrict__ seq,
    const float* __restrict__ emb,
    const float* __restrict__ gamma, const float* __restrict__ beta,
    const float* __restrict__ bv,
    const float* __restrict__ kmvm, const float* __restrict__ cvec,
    const float* __restrict__ lb, const short* __restrict__ Wfrag,
    short* __restrict__ Yx, short* __restrict__ xbuf,
    unsigned* __restrict__ bar, float* __restrict__ zout)
{
  extern __shared__ char smem[];
  short* wlds = (short*)smem;                 // [ntiles<=5][16][64][8] bf16 (81920 B)
  short* zfs  = (short*)(smem + 81920);       // z fragments, XOR-swizzled (16384 B)
  short* vml  = (short*)(smem + 98304);       // Vm bf16 [16][512] (16384 B)
  float* lbl  = (float*)(smem + 114688);      // 17 floats

  const int tid = threadIdx.x, l = tid & 63, w = tid >> 6;
  const int cg = blockIdx.x >> 4;             // blockIdx = cg*16+bg -> XCD = bg%8
  const int bg = blockIdx.x & 15;
  const int ntiles = (cg == 15) ? 5 : 4;

  // ---- stage constants ----
  for (int i = tid; i < NMOV * E_; i += 512)
    vml[i] = f2bf(kmvm[NMOV * E_ + i]);       // Vm = kmvm[1]
  if (tid < 17) lbl[tid] = lb[tid];
  {
    const bf16x8* src = (const bf16x8*)(Wfrag + (size_t)(cg * 4) * 16 * 64 * 8);
    bf16x8* dst = (bf16x8*)wlds;
    for (int i = tid; i < ntiles * 16 * 64; i += 512) dst[i] = src[i];
  }

  // ---- time-invariant per-lane vectors in registers ----
  float cw[8], bw[8], gw[8], bb[8];
  *(float4*)&cw[0] = *(const float4*)(cvec  + l * 8);
  *(float4*)&cw[4] = *(const float4*)(cvec  + l * 8 + 4);
  *(float4*)&bw[0] = *(const float4*)(bv    + l * 8);
  *(float4*)&bw[4] = *(const float4*)(bv    + l * 8 + 4);
  *(float4*)&gw[0] = *(const float4*)(gamma + l * 8);
  *(float4*)&gw[4] = *(const float4*)(gamma + l * 8 + 4);
  *(float4*)&bb[0] = *(const float4*)(beta  + l * 8);
  *(float4*)&bb[4] = *(const float4*)(beta  + l * 8 + 4);

  // ---- per-wave state: 2 batches ----
  const int b0 = bg * 16 + w * 2;
  float zr[2][8];
  #pragma unroll
  for (int bi = 0; bi < 2; ++bi) {
    *(float4*)&zr[bi][0] = *(const float4*)(hidden + (size_t)(b0 + bi) * E_ + l * 8);
    *(float4*)&zr[bi][4] = *(const float4*)(hidden + (size_t)(b0 + bi) * E_ + l * 8 + 4);
  }

  // ---- publish x_0 (this WG owns batch bg*16+cg) ----
  const int bpub = bg * 16 + cg;
  if (w == 7) {
    int idx = seq[bpub * T_];
    float4 e0 = *(const float4*)(emb + (size_t)idx * E_ + l * 8);
    float4 e1 = *(const float4*)(emb + (size_t)idx * E_ + l * 8 + 4);
    short tmp[8] = {f2bf(e0.x), f2bf(e0.y), f2bf(e0.z), f2bf(e0.w),
                    f2bf(e1.x), f2bf(e1.y), f2bf(e1.z), f2bf(e1.w)};
    *(bf16x8*)(xbuf + (size_t)bpub * E_ + l * 8) = *(const bf16x8*)tmp;
  }
  __syncthreads();
  if (tid == 0) {
    __hip_atomic_fetch_add(&bar[bg * 32], 1u, __ATOMIC_RELEASE, __HIP_MEMORY_SCOPE_AGENT);
    while (__hip_atomic_load(&bar[bg * 32], __ATOMIC_ACQUIRE, __HIP_MEMORY_SCOPE_AGENT) < 16u)
      __builtin_amdgcn_s_sleep(1);
  }
  __syncthreads();

  unsigned rnd = 2;
  #pragma unroll 1
  for (int t = 0; t < T_; ++t) {
    const int p = t & 1;
    // ---- read x_t, update z, stage z fragments ----
    #pragma unroll
    for (int bi = 0; bi < 2; ++bi) {
      bf16x8 xv = *(const bf16x8*)(xbuf + ((size_t)p * B_ + b0 + bi) * E_ + l * 8);
      short tmp[8];
      #pragma unroll
      for (int j = 0; j < 8; ++j) {
        zr[bi][j] += bf2f(xv[j]) * SQRTE;
        tmp[j] = f2bf(zr[bi][j]);
      }
      const int ks = l >> 2;
      const int u  = ((l & 3) << 4) | (w * 2 + bi);
      *(bf16x8*)&zfs[((ks << 6) + (u ^ (ks & 7))) * 8] = *(const bf16x8*)tmp;
    }
    // ---- publisher: early-issue emb row for t+1 ----
    float4 e0, e1;
    const bool pubv = (w == 7) && (t + 1 < T_);
    if (pubv) {
      int idx = seq[bpub * T_ + t + 1];
      e0 = *(const float4*)(emb + (size_t)idx * E_ + l * 8);
      e1 = *(const float4*)(emb + (size_t)idx * E_ + l * 8 + 4);
    }
    __syncthreads();

    // ---- phase A: MFMA from LDS (waves 0-3, +wave4 for cg15's 5th tile) ----
    for (int lt = w; lt < ntiles; lt += 4) {
      f32x4 acc = {0.f, 0.f, 0.f, 0.f};
      #pragma unroll
      for (int ks = 0; ks < 16; ++ks) {
        bf16x8 wf = *(const bf16x8*)&wlds[((lt * 16 + ks) * 64 + l) * 8];
        bf16x8 zb = *(const bf16x8*)&zfs[((ks << 6) + (l ^ (ks & 7))) * 8];
        acc = __builtin_amdgcn_mfma_f32_16x16x32_bf16(wf, zb, acc, 0, 0, 0);
      }
      const int gt = cg * 4 + lt;
      short o4[4];
      #pragma unroll
      for (int r = 0; r < 4; ++r) o4[r] = f2bf(acc[r]);
      *(bf16x4*)(Yx + (((size_t)(p * NBG + bg) * 16) + (l & 15)) * YSTR
                    + gt * 16 + ((l >> 4) << 2)) = *(const bf16x4*)o4;
    }
    if (pubv) {
      short tmp[8] = {f2bf(e0.x), f2bf(e0.y), f2bf(e0.z), f2bf(e0.w),
                      f2bf(e1.x), f2bf(e1.y), f2bf(e1.z), f2bf(e1.w)};
      *(bf16x8*)(xbuf + ((size_t)((t + 1) & 1) * B_ + bpub) * E_ + l * 8) = *(const bf16x8*)tmp;
    }
    __syncthreads();                 // all waves' stores drained (vmcnt(0) at barrier)

    // ---- one release/acquire sync per step (16 WGs of this bg) ----
    if (tid == 0) {
      __hip_atomic_fetch_add(&bar[bg * 32], 1u, __ATOMIC_RELEASE, __HIP_MEMORY_SCOPE_AGENT);
      const unsigned tgt = rnd * 16u;
      while (__hip_atomic_load(&bar[bg * 32], __ATOMIC_ACQUIRE, __HIP_MEMORY_SCOPE_AGENT) < tgt)
        __builtin_amdgcn_s_sleep(1);
    }
    ++rnd;
    __syncthreads();

    // ---- phase B: softmax + PV + LayerNorm (redundant per cg) ----
    const short* Yb = Yx + ((size_t)(p * NBG + bg) * 16) * YSTR;
    #pragma unroll
    for (int bi = 0; bi < 2; ++bi) {
      const short* Yr = Yb + (size_t)(w * 2 + bi) * YSTR;
      const bf16x8 wv = *(const bf16x8*)(Yr + l * 8);          // z@A slice
      const bf16x8 vv = *(const bf16x8*)(Yr + 512 + l * 8);    // z@Wv slice
      const bf16x8 m0 = *(const bf16x8*)(Yr + 1024);           // mover logits 0-7
      const bf16x8 m1 = *(const bf16x8*)(Yr + 1032);           // mover logits 8-15

      float part = 0.f;
      #pragma unroll
      for (int j = 0; j < 8; ++j) part += (bf2f(wv[j]) + cw[j]) * zr[bi][j];

      float lgt[17];
      lgt[0] = (wredsum(part) + lbl[16]) * SCALE;
      #pragma unroll
      for (int m = 0; m < 8; ++m) lgt[m + 1] = (bf2f(m0[m]) + lbl[m]) * SCALE;
      #pragma unroll
      for (int m = 0; m < 8; ++m) lgt[m + 9] = (bf2f(m1[m]) + lbl[m + 8]) * SCALE;

      float mx = lgt[0];
      #pragma unroll
      for (int n = 1; n < 17; ++n) mx = fmaxf(mx, lgt[n]);
      float att[17], den = 0.f;
      #pragma unroll
      for (int n = 0; n < 17; ++n) { att[n] = __expf(lgt[n] - mx); den += att[n]; }
      const float rden = 1.f / den;

      float u[8];
      #pragma unroll
      for (int j = 0; j < 8; ++j) u[j] = att[0] * (bf2f(vv[j]) + bw[j]);
      #pragma unroll
      for (int m = 0; m < 16; ++m) {
        const bf16x8 vm = *(const bf16x8*)&vml[m * E_ + l * 8];
        #pragma unroll
        for (int j = 0; j < 8; ++j) u[j] += att[m + 1] * bf2f(vm[j]);
      }
      #pragma unroll
      for (int j = 0; j < 8; ++j) u[j] = zr[bi][j] + u[j] * rden;

      float s1 = 0.f, s2 = 0.f;
      #pragma unroll
      for (int j = 0; j < 8; ++j) { s1 += u[j]; s2 += u[j] * u[j]; }
      s1 = wredsum(s1); s2 = wredsum(s2);
      const float mean = s1 * (1.f / 512.f);
      const float var  = s2 * (1.f / 512.f) - mean * mean;
      const float rstd = rsqrtf(var + 1e-6f);
      #pragma unroll
      for (int j = 0; j < 8; ++j)
        zr[bi][j] = (u[j] - mean) * rstd * gw[j] + bb[j];
    }
  }

  if (cg == 0) {
    #pragma unroll
    for (int bi = 0; bi < 2; ++bi) {
      *(float4*)(zout + (size_t)(b0 + bi) * E_ + l * 8)     = *(float4*)&zr[bi][0];
      *(float4*)(zout + (size_t)(b0 + bi) * E_ + l * 8 + 4) = *(float4*)&zr[bi][4];
    }
  }
}

// ---------------- K8: logits = z @ vocab_W + vocab_b (bf16 MFMA) -----------
#define K2_SMEM (128 * ZSTR * 2)

__global__ __launch_bounds__(512, 2) void k_logits(
    const float* __restrict__ z, const float* __restrict__ W,
    const float* __restrict__ bia, float* __restrict__ out)
{
  extern __shared__ short zl[];                 // [128][ZSTR] bf16
  const int tid = threadIdx.x;
  const int btile = blockIdx.x & 1;
  const int vt = blockIdx.x >> 1;
  for (int i = tid; i < 128 * 128; i += 512) {
    int row = i >> 7, c4 = (i & 127) << 2;
    float4 zv = *(const float4*)(z + (size_t)(btile * 128 + row) * E_ + c4);
    short* d = zl + row * ZSTR + c4;
    d[0] = f2bf(zv.x); d[1] = f2bf(zv.y); d[2] = f2bf(zv.z); d[3] = f2bf(zv.w);
  }
  __syncthreads();
  const int lane = tid & 63, w = tid >> 6;
  const int vc = vt * 128 + w * 16 + (lane & 15);
  const int kq = (lane >> 4) * 8;
  f32x4 acc[8];
  #pragma unroll
  for (int rt = 0; rt < 8; ++rt) acc[rt] = (f32x4){0.f, 0.f, 0.f, 0.f};
  for (int ks = 0; ks < 16; ++ks) {
    bf16x8 bf;
    #pragma unroll
    for (int j = 0; j < 8; ++j)
      bf[j] = f2bf(W[(size_t)(ks * 32 + kq + j) * V_ + vc]);
    #pragma unroll
    for (int rt = 0; rt < 8; ++rt) {
      bf16x8 a = *(const bf16x8*)&zl[(rt * 16 + (lane & 15)) * ZSTR + ks * 32 + kq];
      acc[rt] = __builtin_amdgcn_mfma_f32_16x16x32_bf16(a, bf, acc[rt], 0, 0, 0);
    }
  }
  const float bbv = bia[vc];
  #pragma unroll
  for (int rt = 0; rt < 8; ++rt)
    #pragma unroll
    for (int r = 0; r < 4; ++r)
      out[(size_t)(btile * 128 + rt * 16 + (lane >> 4) * 4 + r) * V_ + vc] = acc[rt][r] + bbv;
}

// ---------------- K9: in-place log_softmax over vocab ----------------------
__global__ void k_logsoftmax(float* __restrict__ y)
{
  float* L = y + (size_t)blockIdx.x * V_;
  float m = -3.402823466e+38f, s = 0.f;
  for (int i = threadIdx.x; i < V_; i += 256) {
    float l = L[i];
    if (l > m) { s = s * __expf(m - l) + 1.f; m = l; }
    else       { s += __expf(l - m); }
  }
  #pragma unroll
  for (int k = 1; k < 64; k <<= 1) {
    float m2 = __shfl_xor(m, k, 64);
    float s2 = __shfl_xor(s, k, 64);
    float M = fmaxf(m, m2);
    s = s * __expf(m - M) + s2 * __expf(m2 - M);
    m = M;
  }
  __shared__ float ms[4], ss[4];
  if ((threadIdx.x & 63) == 0) { ms[threadIdx.x >> 6] = m; ss[threadIdx.x >> 6] = s; }
  __syncthreads();
  float M = fmaxf(fmaxf(ms[0], ms[1]), fmaxf(ms[2], ms[3]));
  float S = ss[0] * __expf(ms[0] - M) + ss[1] * __expf(ms[1] - M) +
            ss[2] * __expf(ms[2] - M) + ss[3] * __expf(ms[3] - M);
  const float lse = M + logf(S);
  for (int i = threadIdx.x; i < V_; i += 256) L[i] -= lse;
}

#define SCAN_SMEM 114816

extern "C" void kernel_launch(void* const* d_in, const int* in_sizes, int n_in,
                              void* d_out, int out_size, void* d_ws, size_t ws_size,
                              hipStream_t stream) {
  const float* hidden = (const float*)d_in[0];
  const int*   seq    = (const int*)  d_in[1];
  const float* emb    = (const float*)d_in[2];
  const float* Wq     = (const float*)d_in[3];
  const float* bq     = (const float*)d_in[4];
  const float* Wk     = (const float*)d_in[5];
  const float* bk     = (const float*)d_in[6];
  const float* Wv     = (const float*)d_in[7];
  const float* bv     = (const float*)d_in[8];
  const float* mover  = (const float*)d_in[9];
  const float* gamma  = (const float*)d_in[10];
  const float* beta   = (const float*)d_in[11];
  const float* vocabW = (const float*)d_in[12];
  const float* vocabB = (const float*)d_in[13];

  float* zoutp = (float*)d_out;                 // (256,1,512)
  float* yout  = zoutp + (size_t)B_ * E_;       // (256,1,32000); scratch until k_logits

  // scratch inside yout (all overwritten by k_logits afterwards)
  short*    Wfrag = (short*)yout;               // 65*16*64*8 = 532480 bf16
  float*    A     = yout + 266240;              // 512*512
  float*    Wqk   = A + 262144;                 // 512*16
  float*    cvec  = Wqk + 8192;                 // 512
  float*    lbp   = cvec + 512;                 // 17 (pad 32)
  float*    kmvmS = lbp + 32;                   // 2*16*512
  short*    Yx    = (short*)(kmvmS + 16384);    // [2][16][16][1056] bf16 = 540672
  short*    xbuf  = Yx + 540672;                // [2][256][512] bf16 = 262144
  unsigned* bar   = (unsigned*)(xbuf + 262144); // 16 counters, 128B apart

  hipMemsetAsync(bar, 0, 16 * 128, stream);
  hipLaunchKernelGGL(k_movers, dim3(32), dim3(256), 0, stream, Wk, bk, Wv, bv, mover, kmvmS);
  hipLaunchKernelGGL(k_gemmA,  dim3(1024), dim3(64), 0, stream, Wq, Wk, A);
  hipLaunchKernelGGL(k_wqk,    dim3(512), dim3(64), 0, stream, Wq, kmvmS, Wqk);
  hipLaunchKernelGGL(k_cvec,   dim3(8), dim3(64), 0, stream, Wq, Wk, bq, bk, cvec);
  hipLaunchKernelGGL(k_lb,     dim3(1), dim3(64), 0, stream, bq, bk, kmvmS, lbp);
  hipLaunchKernelGGL(k_pack,   dim3(NT * 16), dim3(64), 0, stream, A, Wv, Wqk, Wfrag);

  hipFuncSetAttribute((const void*)k_scan3, hipFuncAttributeMaxDynamicSharedMemorySize, SCAN_SMEM);
  void* args[] = {(void*)&hidden, (void*)&seq, (void*)&emb,
                  (void*)&gamma, (void*)&beta, (void*)&bv,
                  (void*)&kmvmS, (void*)&cvec, (void*)&lbp, (void*)&Wfrag,
                  (void*)&Yx, (void*)&xbuf, (void*)&bar, (void*)&zoutp};
  hipLaunchCooperativeKernel((const void*)k_scan3, dim3(NCG * NBG), dim3(512),
                             args, SCAN_SMEM, stream);

  hipFuncSetAttribute((const void*)k_logits, hipFuncAttributeMaxDynamicSharedMemorySize, K2_SMEM);
  hipLaunchKernelGGL(k_logits, dim3(500), dim3(512), K2_SMEM, stream, zoutp, vocabW, vocabB, yout);
  hipLaunchKernelGGL(k_logsoftmax, dim3(256), dim3(256), 0, stream, yout);
}

// Round 4
// 2309.345 us; speedup vs baseline: 4.2164x; 1.7551x over previous
//
#include <hip/hip_runtime.h>

#define B_ 256
#define T_ 256
#define E_ 512
#define V_ 32000
#define NMOV 16
#define NT 65              // column tiles: A(32) | Wv(32) | Wqk(1)
#define NCG 16             // column groups
#define NBG 16             // batch groups
#define YSTR 1056          // Y exchange row stride (bf16 units)
#define ZSTR 520           // k_logits LDS stride

#define SQRTE 22.62741699796952f
#define SCALE 0.04419417382415922f   // 1/sqrt(512)

typedef __attribute__((ext_vector_type(8))) short bf16x8;
typedef __attribute__((ext_vector_type(4))) short bf16x4;
typedef __attribute__((ext_vector_type(4))) float f32x4;
typedef unsigned long long u64;

__device__ __forceinline__ short f2bf(float f) {
  unsigned u = __float_as_uint(f);
  u += 0x7fffu + ((u >> 16) & 1u);          // RNE
  return (short)(u >> 16);
}
__device__ __forceinline__ float bf2f(short s) {
  return __uint_as_float(((unsigned)(unsigned short)s) << 16);
}

// DPP wave64 sum: ~60cyc VALU chain (vs ~600cyc ds_bpermute shfl chain)
__device__ __forceinline__ float wredsum(float v) {
  int x;
  x = __builtin_amdgcn_update_dpp(0, __float_as_int(v), 0xB1, 0xF, 0xF, true);  // quad xor1
  v += __int_as_float(x);
  x = __builtin_amdgcn_update_dpp(0, __float_as_int(v), 0x4E, 0xF, 0xF, true);  // quad xor2
  v += __int_as_float(x);
  x = __builtin_amdgcn_update_dpp(0, __float_as_int(v), 0x141, 0xF, 0xF, true); // row_half_mirror
  v += __int_as_float(x);
  x = __builtin_amdgcn_update_dpp(0, __float_as_int(v), 0x140, 0xF, 0xF, true); // row_mirror
  v += __int_as_float(x);
  x = __builtin_amdgcn_update_dpp(0, __float_as_int(v), 0x142, 0xF, 0xF, true); // row_bcast15
  v += __int_as_float(x);
  x = __builtin_amdgcn_update_dpp(0, __float_as_int(v), 0x143, 0xF, 0xF, true); // row_bcast31
  v += __int_as_float(x);
  return __int_as_float(__builtin_amdgcn_readlane(__float_as_int(v), 63));
}

// relaxed agent-scope (coherence-point) access helpers — no cache maintenance
__device__ __forceinline__ bf16x8 aload8v(const short* p) {
  union { u64 u[2]; bf16x8 v; } c;
  c.u[0] = __hip_atomic_load((const u64*)p,       __ATOMIC_RELAXED, __HIP_MEMORY_SCOPE_AGENT);
  c.u[1] = __hip_atomic_load((const u64*)(p + 4), __ATOMIC_RELAXED, __HIP_MEMORY_SCOPE_AGENT);
  return c.v;
}
__device__ __forceinline__ void astore4v(short* p, bf16x4 v) {
  union { bf16x4 v; u64 u; } c; c.v = v;
  __hip_atomic_store((u64*)p, c.u, __ATOMIC_RELAXED, __HIP_MEMORY_SCOPE_AGENT);
}
__device__ __forceinline__ void astore8s(short* p, const short* v) {
  __hip_atomic_store((u64*)p,       *(const u64*)v,       __ATOMIC_RELAXED, __HIP_MEMORY_SCOPE_AGENT);
  __hip_atomic_store((u64*)(p + 4), *(const u64*)(v + 4), __ATOMIC_RELAXED, __HIP_MEMORY_SCOPE_AGENT);
}

// ---------------- K1: mover K/V: Km = mover@Wk + bk, Vm = mover@Wv + bv ----
__global__ void k_movers(const float* __restrict__ Wk, const float* __restrict__ bk,
                         const float* __restrict__ Wv, const float* __restrict__ bv,
                         const float* __restrict__ mover, float* __restrict__ kmvm)
{
  const int m = blockIdx.x & 15;
  const int s = blockIdx.x >> 4;              // 0 -> K, 1 -> V
  const float* W  = s ? Wv : Wk;
  const float* bb = s ? bv : bk;
  const int c = threadIdx.x * 2;
  float a0 = bb[c], a1 = bb[c + 1];
  for (int r = 0; r < E_; ++r) {
    float mv = mover[m * E_ + r];
    float2 wv = *(const float2*)(W + (size_t)r * E_ + c);
    a0 += mv * wv.x; a1 += mv * wv.y;
  }
  kmvm[(s * NMOV + m) * E_ + c]     = a0;
  kmvm[(s * NMOV + m) * E_ + c + 1] = a1;
}

// ---------------- K2: A = Wq @ Wk^T (bf16 MFMA, f32 out) -------------------
__global__ void k_gemmA(const float* __restrict__ Wq, const float* __restrict__ Wk,
                        float* __restrict__ A)
{
  const int ti = blockIdx.x >> 5, tj = blockIdx.x & 31;
  const int l = threadIdx.x, r16 = l & 15, kq = (l >> 4) * 8;
  f32x4 acc = {0.f, 0.f, 0.f, 0.f};
  for (int ks = 0; ks < 16; ++ks) {
    const float* ap = Wq + (size_t)(ti * 16 + r16) * E_ + ks * 32 + kq;
    const float* bp = Wk + (size_t)(tj * 16 + r16) * E_ + ks * 32 + kq;
    bf16x8 a, b;
    #pragma unroll
    for (int j = 0; j < 8; ++j) { a[j] = f2bf(ap[j]); b[j] = f2bf(bp[j]); }
    acc = __builtin_amdgcn_mfma_f32_16x16x32_bf16(a, b, acc, 0, 0, 0);
  }
  #pragma unroll
  for (int r = 0; r < 4; ++r)
    A[(size_t)(ti * 16 + (l >> 4) * 4 + r) * E_ + tj * 16 + r16] = acc[r];
}

// ---------------- K3: Wqk[i][m] = sum_j Wq[i][j] * Km[m][j] ----------------
__global__ void k_wqk(const float* __restrict__ Wq, const float* __restrict__ kmvm,
                      float* __restrict__ Wqk)
{
  const int i = blockIdx.x;
  const int l = threadIdx.x, m = l & 15, sl = l >> 4;
  float p = 0.f;
  for (int j = sl * 128; j < sl * 128 + 128; ++j)
    p += Wq[(size_t)i * E_ + j] * kmvm[(size_t)m * E_ + j];
  p += __shfl_xor(p, 16, 64);
  p += __shfl_xor(p, 32, 64);
  if (l < 16) Wqk[i * 16 + m] = p;
}

// ---------------- K4: cvec[i] = Wq[i]·bk + Wk[i]·bq ------------------------
__global__ void k_cvec(const float* __restrict__ Wq, const float* __restrict__ Wk,
                       const float* __restrict__ bq, const float* __restrict__ bk,
                       float* __restrict__ cvec)
{
  const int i = blockIdx.x * 64 + threadIdx.x;
  float s = 0.f;
  for (int j = 0; j < E_; ++j)
    s += Wq[(size_t)i * E_ + j] * bk[j] + Wk[(size_t)i * E_ + j] * bq[j];
  cvec[i] = s;
}

// ---------------- K5: lb[m] = bq·Km[m] (m<16), lb[16] = bq·bk --------------
__global__ void k_lb(const float* __restrict__ bq, const float* __restrict__ bk,
                     const float* __restrict__ kmvm, float* __restrict__ lb)
{
  const int l = threadIdx.x;
  if (l < 16) {
    float s = 0.f;
    for (int j = 0; j < E_; ++j) s += bq[j] * kmvm[(size_t)l * E_ + j];
    lb[l] = s;
  } else if (l == 16) {
    float s = 0.f;
    for (int j = 0; j < E_; ++j) s += bq[j] * bk[j];
    lb[16] = s;
  }
}

// ---------------- K6: pack Wcat = [A | Wv | Wqk] into MFMA fragment order --
__global__ void k_pack(const float* __restrict__ A, const float* __restrict__ Wv,
                       const float* __restrict__ Wqk, short* __restrict__ Wfrag)
{
  const int blk = blockIdx.x;          // ct*16 + ks
  const int ct = blk >> 4, ks = blk & 15;
  const int l = threadIdx.x;
  const int c = ct * 16 + (l & 15);
  const int r0 = ks * 32 + (l >> 4) * 8;
  short v[8];
  #pragma unroll
  for (int j = 0; j < 8; ++j) {
    const int r = r0 + j;
    float x;
    if (c < 512)       x = A[(size_t)r * E_ + c];
    else if (c < 1024) x = Wv[(size_t)r * E_ + (c - 512)];
    else               x = Wqk[r * 16 + (c - 1024)];
    v[j] = f2bf(x);
  }
  *(bf16x8*)(Wfrag + ((size_t)blk * 64 + l) * 8) = *(const bf16x8*)v;
}

// ---------------- K7: LDS-resident partitioned scan, flag-sync'd -----------
// 256 WGs = 16 cg x 16 bg, 512 threads (8 waves), 1 WG/CU.
// Cross-WG traffic via relaxed agent atomics (coherence-point, no cache ops).
// Per step: stage z -> syncthreads -> phase A (waves 0-3 MFMA + Y store +
// per-wave waitcnt + flag release; wave 3 also publishes x from regs) ->
// all-lane flag spin (64 lanes x 64 flags) -> x prefetch -> phase B.
__global__ __launch_bounds__(512, 2) void k_scan4(
    const float* __restrict__ hidden, const int* __restrict__ seq,
    const float* __restrict__ emb,
    const float* __restrict__ gamma, const float* __restrict__ beta,
    const float* __restrict__ bv,
    const float* __restrict__ kmvm, const float* __restrict__ cvec,
    const float* __restrict__ lb, const short* __restrict__ Wfrag,
    short* __restrict__ Yx, short* __restrict__ xbuf,
    unsigned* __restrict__ flags, float* __restrict__ zout)
{
  extern __shared__ char smem[];
  short* wlds = (short*)smem;                 // <=5 tiles x 16KB = 81920 B
  short* zfs  = (short*)(smem + 81920);       // 16384 B
  short* vml  = (short*)(smem + 98304);       // 16384 B
  float* cl   = (float*)(smem + 114688);      // 2048 B
  float* bvl  = (float*)(smem + 116736);      // 2048 B
  float* gl   = (float*)(smem + 118784);      // 2048 B
  float* bl   = (float*)(smem + 120832);      // 2048 B
  float* lbl  = (float*)(smem + 122880);      // 128 B

  const int tid = threadIdx.x, l = tid & 63, w = tid >> 6;
  const int cg = blockIdx.x >> 4;             // blockIdx = cg*16+bg -> XCD = bg%8
  const int bg = blockIdx.x & 15;
  const int ntiles = (cg == 15) ? 5 : 4;

  // ---- stage constants ----
  for (int i = tid; i < NMOV * E_; i += 512)
    vml[i] = f2bf(kmvm[NMOV * E_ + i]);       // Vm = kmvm[1]
  for (int i = tid; i < E_; i += 512) {
    cl[i] = cvec[i]; bvl[i] = bv[i]; gl[i] = gamma[i]; bl[i] = beta[i];
  }
  if (tid < 17) lbl[tid] = lb[tid];
  {
    const bf16x8* src = (const bf16x8*)(Wfrag + (size_t)(cg * 4) * 16 * 64 * 8);
    bf16x8* dst = (bf16x8*)wlds;
    for (int i = tid; i < ntiles * 16 * 64; i += 512) dst[i] = src[i];
  }

  // ---- per-wave state: 2 batches ----
  const int b0 = bg * 16 + w * 2;
  float zr[2][8];
  #pragma unroll
  for (int bi = 0; bi < 2; ++bi) {
    *(float4*)&zr[bi][0] = *(const float4*)(hidden + (size_t)(b0 + bi) * E_ + l * 8);
    *(float4*)&zr[bi][4] = *(const float4*)(hidden + (size_t)(b0 + bi) * E_ + l * 8 + 4);
  }
  __syncthreads();                            // consts staged

  const int bpub = bg * 16 + cg;
  unsigned* myflag = flags + ((size_t)(bg * 16 + cg) * 32 + w);
  unsigned* pollp  = flags + ((size_t)(bg * 16 + (l >> 2)) * 32 + (l & 3));

  // ---- publisher pipeline state (wave 3 only) ----
  int idxn = 0; float4 ep0 = {0,0,0,0}, ep1 = {0,0,0,0};
  if (w == 3) {
    // publish x0
    int i0 = seq[bpub * T_];
    float4 a0 = *(const float4*)(emb + (size_t)i0 * E_ + l * 8);
    float4 a1 = *(const float4*)(emb + (size_t)i0 * E_ + l * 8 + 4);
    short tmp[8] = {f2bf(a0.x), f2bf(a0.y), f2bf(a0.z), f2bf(a0.w),
                    f2bf(a1.x), f2bf(a1.y), f2bf(a1.z), f2bf(a1.w)};
    astore8s(xbuf + (size_t)bpub * E_ + l * 8, tmp);
    // prefetch x1 data + seq[2]
    int i1 = seq[bpub * T_ + 1];
    ep0 = *(const float4*)(emb + (size_t)i1 * E_ + l * 8);
    ep1 = *(const float4*)(emb + (size_t)i1 * E_ + l * 8 + 4);
    idxn = seq[bpub * T_ + 2];
  }
  if (w < 4) {
    asm volatile("s_waitcnt vmcnt(0)" ::: "memory");
    if (l == 0)
      __hip_atomic_store(myflag, 1u, __ATOMIC_RELAXED, __HIP_MEMORY_SCOPE_AGENT);
  }
  while (__hip_atomic_load(pollp, __ATOMIC_RELAXED, __HIP_MEMORY_SCOPE_AGENT) < 1u)
    __builtin_amdgcn_s_sleep(2);
  asm volatile("" ::: "memory");

  // prefetch x0 for own batches
  bf16x8 xp0 = aload8v(xbuf + (size_t)b0 * E_ + l * 8);
  bf16x8 xp1 = aload8v(xbuf + (size_t)(b0 + 1) * E_ + l * 8);

  #pragma unroll 1
  for (int t = 0; t < T_; ++t) {
    const int p = t & 1;
    // ---- z += x_t; stage z fragments ----
    {
      short ta[8], tb[8];
      #pragma unroll
      for (int j = 0; j < 8; ++j) {
        zr[0][j] += bf2f(xp0[j]) * SQRTE; ta[j] = f2bf(zr[0][j]);
        zr[1][j] += bf2f(xp1[j]) * SQRTE; tb[j] = f2bf(zr[1][j]);
      }
      const int ks = l >> 2;
      const int ua = ((l & 3) << 4) | (w * 2);
      const int ub = ua | 1;
      *(bf16x8*)&zfs[((ks << 6) + (ua ^ (ks & 7))) * 8] = *(const bf16x8*)ta;
      *(bf16x8*)&zfs[((ks << 6) + (ub ^ (ks & 7))) * 8] = *(const bf16x8*)tb;
    }
    __syncthreads();

    // ---- phase A: MFMA + Y store + flag release (waves 0-3) ----
    if (w < 4) {
      for (int lt = w; lt < ntiles; lt += 4) {
        f32x4 acc = {0.f, 0.f, 0.f, 0.f};
        #pragma unroll
        for (int ks = 0; ks < 16; ++ks) {
          bf16x8 wf = *(const bf16x8*)&wlds[((lt * 16 + ks) * 64 + l) * 8];
          bf16x8 zb = *(const bf16x8*)&zfs[((ks << 6) + (l ^ (ks & 7))) * 8];
          acc = __builtin_amdgcn_mfma_f32_16x16x32_bf16(wf, zb, acc, 0, 0, 0);
        }
        const int gt = cg * 4 + lt;
        bf16x4 o;
        #pragma unroll
        for (int r = 0; r < 4; ++r) o[r] = f2bf(acc[r]);
        astore4v(Yx + (((size_t)(p * NBG + bg) * 16) + (l & 15)) * YSTR
                    + gt * 16 + ((l >> 4) << 2), o);
      }
      if (w == 3 && t + 1 < T_) {           // publish x_{t+1} from regs (no load dep)
        short tmp[8] = {f2bf(ep0.x), f2bf(ep0.y), f2bf(ep0.z), f2bf(ep0.w),
                        f2bf(ep1.x), f2bf(ep1.y), f2bf(ep1.z), f2bf(ep1.w)};
        astore8s(xbuf + ((size_t)((t + 1) & 1) * B_ + bpub) * E_ + l * 8, tmp);
      }
      asm volatile("s_waitcnt vmcnt(0)" ::: "memory");
      if (l == 0)
        __hip_atomic_store(myflag, (unsigned)(t + 2), __ATOMIC_RELAXED, __HIP_MEMORY_SCOPE_AGENT);
      if (w == 3) {                          // issue next prefetches AFTER flag
        if (t + 2 < T_) {
          ep0 = *(const float4*)(emb + (size_t)idxn * E_ + l * 8);
          ep1 = *(const float4*)(emb + (size_t)idxn * E_ + l * 8 + 4);
        }
        if (t + 3 < T_) idxn = seq[bpub * T_ + t + 3];
      }
    }

    // ---- all-lane flag spin (one flag per lane) ----
    {
      const unsigned rnd = (unsigned)(t + 2);
      while (__hip_atomic_load(pollp, __ATOMIC_RELAXED, __HIP_MEMORY_SCOPE_AGENT) < rnd)
        __builtin_amdgcn_s_sleep(2);
      asm volatile("" ::: "memory");
    }

    // ---- prefetch x_{t+1} ----
    if (t + 1 < T_) {
      xp0 = aload8v(xbuf + ((size_t)((t + 1) & 1) * B_ + b0) * E_ + l * 8);
      xp1 = aload8v(xbuf + ((size_t)((t + 1) & 1) * B_ + b0 + 1) * E_ + l * 8);
    }

    // ---- phase B: 2 batches interleaved ----
    {
      const short* Yb  = Yx + ((size_t)(p * NBG + bg) * 16) * YSTR;
      const short* Yr0 = Yb + (size_t)(w * 2) * YSTR;
      const short* Yr1 = Yb + (size_t)(w * 2 + 1) * YSTR;
      bf16x8 wv0 = aload8v(Yr0 + l * 8),       wv1 = aload8v(Yr1 + l * 8);
      bf16x8 vv0 = aload8v(Yr0 + 512 + l * 8), vv1 = aload8v(Yr1 + 512 + l * 8);
      bf16x8 ma0 = aload8v(Yr0 + 1024),        ma1 = aload8v(Yr1 + 1024);
      bf16x8 mb0 = aload8v(Yr0 + 1032),        mb1 = aload8v(Yr1 + 1032);

      float cw[8];
      *(float4*)&cw[0] = *(const float4*)&cl[l * 8];
      *(float4*)&cw[4] = *(const float4*)&cl[l * 8 + 4];
      float p0 = 0.f, p1 = 0.f;
      #pragma unroll
      for (int j = 0; j < 8; ++j) {
        p0 += (bf2f(wv0[j]) + cw[j]) * zr[0][j];
        p1 += (bf2f(wv1[j]) + cw[j]) * zr[1][j];
      }
      const float r0 = wredsum(p0);
      const float r1 = wredsum(p1);

      float a0[17], a1[17];
      a0[0] = (r0 + lbl[16]) * SCALE;
      a1[0] = (r1 + lbl[16]) * SCALE;
      #pragma unroll
      for (int m = 0; m < 8; ++m) {
        a0[m + 1] = (bf2f(ma0[m]) + lbl[m]) * SCALE;
        a0[m + 9] = (bf2f(mb0[m]) + lbl[m + 8]) * SCALE;
        a1[m + 1] = (bf2f(ma1[m]) + lbl[m]) * SCALE;
        a1[m + 9] = (bf2f(mb1[m]) + lbl[m + 8]) * SCALE;
      }
      float mx0 = a0[0], mx1 = a1[0];
      #pragma unroll
      for (int n = 1; n < 17; ++n) { mx0 = fmaxf(mx0, a0[n]); mx1 = fmaxf(mx1, a1[n]); }
      float d0 = 0.f, d1 = 0.f;
      #pragma unroll
      for (int n = 0; n < 17; ++n) {
        a0[n] = __expf(a0[n] - mx0); d0 += a0[n];
        a1[n] = __expf(a1[n] - mx1); d1 += a1[n];
      }
      const float rd0 = __fdividef(1.f, d0);
      const float rd1 = __fdividef(1.f, d1);

      float bw[8];
      *(float4*)&bw[0] = *(const float4*)&bvl[l * 8];
      *(float4*)&bw[4] = *(const float4*)&bvl[l * 8 + 4];
      float u0[8], u1[8];
      #pragma unroll
      for (int j = 0; j < 8; ++j) {
        u0[j] = a0[0] * (bf2f(vv0[j]) + bw[j]);
        u1[j] = a1[0] * (bf2f(vv1[j]) + bw[j]);
      }
      #pragma unroll
      for (int m = 0; m < 16; ++m) {
        const bf16x8 vm = *(const bf16x8*)&vml[m * E_ + l * 8];
        #pragma unroll
        for (int j = 0; j < 8; ++j) {
          const float f = bf2f(vm[j]);
          u0[j] += a0[m + 1] * f;
          u1[j] += a1[m + 1] * f;
        }
      }
      #pragma unroll
      for (int j = 0; j < 8; ++j) {
        u0[j] = zr[0][j] + u0[j] * rd0;
        u1[j] = zr[1][j] + u1[j] * rd1;
      }

      float s10 = 0.f, s20 = 0.f, s11 = 0.f, s21 = 0.f;
      #pragma unroll
      for (int j = 0; j < 8; ++j) {
        s10 += u0[j]; s20 += u0[j] * u0[j];
        s11 += u1[j]; s21 += u1[j] * u1[j];
      }
      s10 = wredsum(s10); s20 = wredsum(s20);
      s11 = wredsum(s11); s21 = wredsum(s21);
      const float mean0 = s10 * (1.f / 512.f);
      const float mean1 = s11 * (1.f / 512.f);
      const float rstd0 = rsqrtf(s20 * (1.f / 512.f) - mean0 * mean0 + 1e-6f);
      const float rstd1 = rsqrtf(s21 * (1.f / 512.f) - mean1 * mean1 + 1e-6f);

      float gw[8], bb[8];
      *(float4*)&gw[0] = *(const float4*)&gl[l * 8];
      *(float4*)&gw[4] = *(const float4*)&gl[l * 8 + 4];
      *(float4*)&bb[0] = *(const float4*)&bl[l * 8];
      *(float4*)&bb[4] = *(const float4*)&bl[l * 8 + 4];
      #pragma unroll
      for (int j = 0; j < 8; ++j) {
        zr[0][j] = (u0[j] - mean0) * rstd0 * gw[j] + bb[j];
        zr[1][j] = (u1[j] - mean1) * rstd1 * gw[j] + bb[j];
      }
    }
  }

  if (cg == 0) {
    #pragma unroll
    for (int bi = 0; bi < 2; ++bi) {
      *(float4*)(zout + (size_t)(b0 + bi) * E_ + l * 8)     = *(float4*)&zr[bi][0];
      *(float4*)(zout + (size_t)(b0 + bi) * E_ + l * 8 + 4) = *(float4*)&zr[bi][4];
    }
  }
}

// ---------------- K8: logits = z @ vocab_W + vocab_b (bf16 MFMA) -----------
#define K2_SMEM (128 * ZSTR * 2)

__global__ __launch_bounds__(512, 2) void k_logits(
    const float* __restrict__ z, const float* __restrict__ W,
    const float* __restrict__ bia, float* __restrict__ out)
{
  extern __shared__ short zl[];                 // [128][ZSTR] bf16
  const int tid = threadIdx.x;
  const int btile = blockIdx.x & 1;
  const int vt = blockIdx.x >> 1;
  for (int i = tid; i < 128 * 128; i += 512) {
    int row = i >> 7, c4 = (i & 127) << 2;
    float4 zv = *(const float4*)(z + (size_t)(btile * 128 + row) * E_ + c4);
    short* d = zl + row * ZSTR + c4;
    d[0] = f2bf(zv.x); d[1] = f2bf(zv.y); d[2] = f2bf(zv.z); d[3] = f2bf(zv.w);
  }
  __syncthreads();
  const int lane = tid & 63, w = tid >> 6;
  const int vc = vt * 128 + w * 16 + (lane & 15);
  const int kq = (lane >> 4) * 8;
  f32x4 acc[8];
  #pragma unroll
  for (int rt = 0; rt < 8; ++rt) acc[rt] = (f32x4){0.f, 0.f, 0.f, 0.f};
  for (int ks = 0; ks < 16; ++ks) {
    bf16x8 bf;
    #pragma unroll
    for (int j = 0; j < 8; ++j)
      bf[j] = f2bf(W[(size_t)(ks * 32 + kq + j) * V_ + vc]);
    #pragma unroll
    for (int rt = 0; rt < 8; ++rt) {
      bf16x8 a = *(const bf16x8*)&zl[(rt * 16 + (lane & 15)) * ZSTR + ks * 32 + kq];
      acc[rt] = __builtin_amdgcn_mfma_f32_16x16x32_bf16(a, bf, acc[rt], 0, 0, 0);
    }
  }
  const float bbv = bia[vc];
  #pragma unroll
  for (int rt = 0; rt < 8; ++rt)
    #pragma unroll
    for (int r = 0; r < 4; ++r)
      out[(size_t)(btile * 128 + rt * 16 + (lane >> 4) * 4 + r) * V_ + vc] = acc[rt][r] + bbv;
}

// ---------------- K9: in-place log_softmax over vocab ----------------------
__global__ void k_logsoftmax(float* __restrict__ y)
{
  float* L = y + (size_t)blockIdx.x * V_;
  float m = -3.402823466e+38f, s = 0.f;
  for (int i = threadIdx.x; i < V_; i += 256) {
    float l = L[i];
    if (l > m) { s = s * __expf(m - l) + 1.f; m = l; }
    else       { s += __expf(l - m); }
  }
  #pragma unroll
  for (int k = 1; k < 64; k <<= 1) {
    float m2 = __shfl_xor(m, k, 64);
    float s2 = __shfl_xor(s, k, 64);
    float M = fmaxf(m, m2);
    s = s * __expf(m - M) + s2 * __expf(m2 - M);
    m = M;
  }
  __shared__ float ms[4], ss[4];
  if ((threadIdx.x & 63) == 0) { ms[threadIdx.x >> 6] = m; ss[threadIdx.x >> 6] = s; }
  __syncthreads();
  float M = fmaxf(fmaxf(ms[0], ms[1]), fmaxf(ms[2], ms[3]));
  float S = ss[0] * __expf(ms[0] - M) + ss[1] * __expf(ms[1] - M) +
            ss[2] * __expf(ms[2] - M) + ss[3] * __expf(ms[3] - M);
  const float lse = M + logf(S);
  for (int i = threadIdx.x; i < V_; i += 256) L[i] -= lse;
}

#define SCAN_SMEM 123008

extern "C" void kernel_launch(void* const* d_in, const int* in_sizes, int n_in,
                              void* d_out, int out_size, void* d_ws, size_t ws_size,
                              hipStream_t stream) {
  const float* hidden = (const float*)d_in[0];
  const int*   seq    = (const int*)  d_in[1];
  const float* emb    = (const float*)d_in[2];
  const float* Wq     = (const float*)d_in[3];
  const float* bq     = (const float*)d_in[4];
  const float* Wk     = (const float*)d_in[5];
  const float* bk     = (const float*)d_in[6];
  const float* Wv     = (const float*)d_in[7];
  const float* bv     = (const float*)d_in[8];
  const float* mover  = (const float*)d_in[9];
  const float* gamma  = (const float*)d_in[10];
  const float* beta   = (const float*)d_in[11];
  const float* vocabW = (const float*)d_in[12];
  const float* vocabB = (const float*)d_in[13];

  float* zoutp = (float*)d_out;                 // (256,1,512)
  float* yout  = zoutp + (size_t)B_ * E_;       // (256,1,32000); scratch until k_logits

  // scratch inside yout (all overwritten by k_logits afterwards)
  short*    Wfrag = (short*)yout;               // 65*16*64*8 = 532480 bf16
  float*    A     = yout + 266240;              // 512*512
  float*    Wqk   = A + 262144;                 // 512*16
  float*    cvec  = Wqk + 8192;                 // 512
  float*    lbp   = cvec + 512;                 // 17 (pad 32)
  float*    kmvmS = lbp + 32;                   // 2*16*512
  short*    Yx    = (short*)(kmvmS + 16384);    // [2][16][16][1056] bf16 = 540672
  short*    xbuf  = Yx + 540672;                // [2][256][512] bf16 = 262144
  unsigned* flags = (unsigned*)(xbuf + 262144); // 16bg x 16cg x 32 uints = 32KB

  hipMemsetAsync(flags, 0, 32768, stream);
  hipLaunchKernelGGL(k_movers, dim3(32), dim3(256), 0, stream, Wk, bk, Wv, bv, mover, kmvmS);
  hipLaunchKernelGGL(k_gemmA,  dim3(1024), dim3(64), 0, stream, Wq, Wk, A);
  hipLaunchKernelGGL(k_wqk,    dim3(512), dim3(64), 0, stream, Wq, kmvmS, Wqk);
  hipLaunchKernelGGL(k_cvec,   dim3(8), dim3(64), 0, stream, Wq, Wk, bq, bk, cvec);
  hipLaunchKernelGGL(k_lb,     dim3(1), dim3(64), 0, stream, bq, bk, kmvmS, lbp);
  hipLaunchKernelGGL(k_pack,   dim3(NT * 16), dim3(64), 0, stream, A, Wv, Wqk, Wfrag);

  hipFuncSetAttribute((const void*)k_scan4, hipFuncAttributeMaxDynamicSharedMemorySize, SCAN_SMEM);
  void* args[] = {(void*)&hidden, (void*)&seq, (void*)&emb,
                  (void*)&gamma, (void*)&beta, (void*)&bv,
                  (void*)&kmvmS, (void*)&cvec, (void*)&lbp, (void*)&Wfrag,
                  (void*)&Yx, (void*)&xbuf, (void*)&flags, (void*)&zoutp};
  hipLaunchCooperativeKernel((const void*)k_scan4, dim3(NCG * NBG), dim3(512),
                             args, SCAN_SMEM, stream);

  hipFuncSetAttribute((const void*)k_logits, hipFuncAttributeMaxDynamicSharedMemorySize, K2_SMEM);
  hipLaunchKernelGGL(k_logits, dim3(500), dim3(512), K2_SMEM, stream, zoutp, vocabW, vocabB, yout);
  hipLaunchKernelGGL(k_logsoftmax, dim3(256), dim3(256), 0, stream, yout);
}

// Round 5
// 1521.157 us; speedup vs baseline: 6.4012x; 1.5182x over previous
//
#include <hip/hip_runtime.h>

#define B_ 256
#define T_ 256
#define E_ 512
#define V_ 32000
#define NMOV 16
#define NT 65              // column tiles: A(32) | Wv(32) | Wqk(1)
#define NCG 16             // column groups
#define NBG 16             // batch groups
#define YSTR 1056          // Y exchange row stride (bf16 units)
#define ZSTR 520           // k_logits LDS stride

#define SQRTE 22.62741699796952f
#define SCALE 0.04419417382415922f   // 1/sqrt(512)

typedef __attribute__((ext_vector_type(8))) short bf16x8;
typedef __attribute__((ext_vector_type(4))) short bf16x4;
typedef __attribute__((ext_vector_type(4))) float f32x4;
typedef unsigned long long u64;

__device__ __forceinline__ short f2bf(float f) {
  unsigned u = __float_as_uint(f);
  u += 0x7fffu + ((u >> 16) & 1u);          // RNE
  return (short)(u >> 16);
}
__device__ __forceinline__ float bf2f(short s) {
  return __uint_as_float(((unsigned)(unsigned short)s) << 16);
}

// DPP wave64 sum (~60cyc VALU chain)
__device__ __forceinline__ float wredsum(float v) {
  int x;
  x = __builtin_amdgcn_update_dpp(0, __float_as_int(v), 0xB1, 0xF, 0xF, true);  // quad xor1
  v += __int_as_float(x);
  x = __builtin_amdgcn_update_dpp(0, __float_as_int(v), 0x4E, 0xF, 0xF, true);  // quad xor2
  v += __int_as_float(x);
  x = __builtin_amdgcn_update_dpp(0, __float_as_int(v), 0x141, 0xF, 0xF, true); // row_half_mirror
  v += __int_as_float(x);
  x = __builtin_amdgcn_update_dpp(0, __float_as_int(v), 0x140, 0xF, 0xF, true); // row_mirror
  v += __int_as_float(x);
  x = __builtin_amdgcn_update_dpp(0, __float_as_int(v), 0x142, 0xF, 0xF, true); // row_bcast15
  v += __int_as_float(x);
  x = __builtin_amdgcn_update_dpp(0, __float_as_int(v), 0x143, 0xF, 0xF, true); // row_bcast31
  v += __int_as_float(x);
  return __int_as_float(__builtin_amdgcn_readlane(__float_as_int(v), 63));
}

// relaxed agent-scope (coherence-point) access helpers — no cache maintenance
__device__ __forceinline__ bf16x8 aload8v(const short* p) {
  union { u64 u[2]; bf16x8 v; } c;
  c.u[0] = __hip_atomic_load((const u64*)p,       __ATOMIC_RELAXED, __HIP_MEMORY_SCOPE_AGENT);
  c.u[1] = __hip_atomic_load((const u64*)(p + 4), __ATOMIC_RELAXED, __HIP_MEMORY_SCOPE_AGENT);
  return c.v;
}
__device__ __forceinline__ void astore4v(short* p, bf16x4 v) {
  union { bf16x4 v; u64 u; } c; c.v = v;
  __hip_atomic_store((u64*)p, c.u, __ATOMIC_RELAXED, __HIP_MEMORY_SCOPE_AGENT);
}

// ---------------- K1: mover K/V: Km = mover@Wk + bk, Vm = mover@Wv + bv ----
__global__ void k_movers(const float* __restrict__ Wk, const float* __restrict__ bk,
                         const float* __restrict__ Wv, const float* __restrict__ bv,
                         const float* __restrict__ mover, float* __restrict__ kmvm)
{
  const int m = blockIdx.x & 15;
  const int s = blockIdx.x >> 4;              // 0 -> K, 1 -> V
  const float* W  = s ? Wv : Wk;
  const float* bb = s ? bv : bk;
  const int c = threadIdx.x * 2;
  float a0 = bb[c], a1 = bb[c + 1];
  for (int r = 0; r < E_; ++r) {
    float mv = mover[m * E_ + r];
    float2 wv = *(const float2*)(W + (size_t)r * E_ + c);
    a0 += mv * wv.x; a1 += mv * wv.y;
  }
  kmvm[(s * NMOV + m) * E_ + c]     = a0;
  kmvm[(s * NMOV + m) * E_ + c + 1] = a1;
}

// ---------------- K2: A = Wq @ Wk^T (bf16 MFMA, f32 out) -------------------
__global__ void k_gemmA(const float* __restrict__ Wq, const float* __restrict__ Wk,
                        float* __restrict__ A)
{
  const int ti = blockIdx.x >> 5, tj = blockIdx.x & 31;
  const int l = threadIdx.x, r16 = l & 15, kq = (l >> 4) * 8;
  f32x4 acc = {0.f, 0.f, 0.f, 0.f};
  for (int ks = 0; ks < 16; ++ks) {
    const float* ap = Wq + (size_t)(ti * 16 + r16) * E_ + ks * 32 + kq;
    const float* bp = Wk + (size_t)(tj * 16 + r16) * E_ + ks * 32 + kq;
    bf16x8 a, b;
    #pragma unroll
    for (int j = 0; j < 8; ++j) { a[j] = f2bf(ap[j]); b[j] = f2bf(bp[j]); }
    acc = __builtin_amdgcn_mfma_f32_16x16x32_bf16(a, b, acc, 0, 0, 0);
  }
  #pragma unroll
  for (int r = 0; r < 4; ++r)
    A[(size_t)(ti * 16 + (l >> 4) * 4 + r) * E_ + tj * 16 + r16] = acc[r];
}

// ---------------- K3: Wqk[i][m] = sum_j Wq[i][j] * Km[m][j] ----------------
__global__ void k_wqk(const float* __restrict__ Wq, const float* __restrict__ kmvm,
                      float* __restrict__ Wqk)
{
  const int i = blockIdx.x;
  const int l = threadIdx.x, m = l & 15, sl = l >> 4;
  float p = 0.f;
  for (int j = sl * 128; j < sl * 128 + 128; ++j)
    p += Wq[(size_t)i * E_ + j] * kmvm[(size_t)m * E_ + j];
  p += __shfl_xor(p, 16, 64);
  p += __shfl_xor(p, 32, 64);
  if (l < 16) Wqk[i * 16 + m] = p;
}

// ---------------- K4: cvec[i] = Wq[i]·bk + Wk[i]·bq ------------------------
__global__ void k_cvec(const float* __restrict__ Wq, const float* __restrict__ Wk,
                       const float* __restrict__ bq, const float* __restrict__ bk,
                       float* __restrict__ cvec)
{
  const int i = blockIdx.x * 64 + threadIdx.x;
  float s = 0.f;
  for (int j = 0; j < E_; ++j)
    s += Wq[(size_t)i * E_ + j] * bk[j] + Wk[(size_t)i * E_ + j] * bq[j];
  cvec[i] = s;
}

// ---------------- K5: lb[m] = bq·Km[m] (m<16), lb[16] = bq·bk --------------
__global__ void k_lb(const float* __restrict__ bq, const float* __restrict__ bk,
                     const float* __restrict__ kmvm, float* __restrict__ lb)
{
  const int l = threadIdx.x;
  if (l < 16) {
    float s = 0.f;
    for (int j = 0; j < E_; ++j) s += bq[j] * kmvm[(size_t)l * E_ + j];
    lb[l] = s;
  } else if (l == 16) {
    float s = 0.f;
    for (int j = 0; j < E_; ++j) s += bq[j] * bk[j];
    lb[16] = s;
  }
}

// ---------------- K6: pack Wcat = [A | Wv | Wqk] into MFMA fragment order --
__global__ void k_pack(const float* __restrict__ A, const float* __restrict__ Wv,
                       const float* __restrict__ Wqk, short* __restrict__ Wfrag)
{
  const int blk = blockIdx.x;          // ct*16 + ks
  const int ct = blk >> 4, ks = blk & 15;
  const int l = threadIdx.x;
  const int c = ct * 16 + (l & 15);
  const int r0 = ks * 32 + (l >> 4) * 8;
  short v[8];
  #pragma unroll
  for (int j = 0; j < 8; ++j) {
    const int r = r0 + j;
    float x;
    if (c < 512)       x = A[(size_t)r * E_ + c];
    else if (c < 1024) x = Wv[(size_t)r * E_ + (c - 512)];
    else               x = Wqk[r * 16 + (c - 1024)];
    v[j] = f2bf(x);
  }
  *(bf16x8*)(Wfrag + ((size_t)blk * 64 + l) * 8) = *(const bf16x8*)v;
}

// ---------------- K7: LDS-resident partitioned scan, single-line flags -----
// 256 WGs = 16 cg x 16 bg, 512 threads (8 waves), 1 WG/CU.
// Per step: stage z -> bar1 -> phase A (waves 0..ntiles-1, 1 MFMA tile each,
// Y store via relaxed agent atomics) -> bar2 (vmcnt drain) -> tid0 stores
// flag[bg][cg]=t+1 (one 128B line per bg) -> wave 0 alone polls the 16 slots
// -> bar3 -> phase B (all waves, 2 batches each). x_t gathered directly from
// emb one step ahead (indices two steps ahead) — off the critical path.
__global__ __launch_bounds__(512, 2) void k_scan5(
    const float* __restrict__ hidden, const int* __restrict__ seq,
    const float* __restrict__ emb,
    const float* __restrict__ gamma, const float* __restrict__ beta,
    const float* __restrict__ bv,
    const float* __restrict__ kmvm, const float* __restrict__ cvec,
    const float* __restrict__ lb, const short* __restrict__ Wfrag,
    short* __restrict__ Yx, unsigned* __restrict__ flags,
    float* __restrict__ zout)
{
  extern __shared__ char smem[];
  short* wlds = (short*)smem;                 // <=5 tiles x 16KB = 81920 B
  short* zfs  = (short*)(smem + 81920);       // 16384 B
  short* vml  = (short*)(smem + 98304);       // 16384 B
  float* cl   = (float*)(smem + 114688);      // 2048 B
  float* bvl  = (float*)(smem + 116736);      // 2048 B
  float* gl   = (float*)(smem + 118784);      // 2048 B
  float* bl   = (float*)(smem + 120832);      // 2048 B
  float* lbl  = (float*)(smem + 122880);      // 128 B

  const int tid = threadIdx.x, l = tid & 63, w = tid >> 6;
  const int cg = blockIdx.x >> 4;
  const int bg = blockIdx.x & 15;
  const int ntiles = (cg == 15) ? 5 : 4;

  // ---- stage constants ----
  for (int i = tid; i < NMOV * E_; i += 512)
    vml[i] = f2bf(kmvm[NMOV * E_ + i]);       // Vm = kmvm[1]
  for (int i = tid; i < E_; i += 512) {
    cl[i] = cvec[i]; bvl[i] = bv[i]; gl[i] = gamma[i]; bl[i] = beta[i];
  }
  if (tid < 17) lbl[tid] = lb[tid];
  {
    const bf16x8* src = (const bf16x8*)(Wfrag + (size_t)(cg * 4) * 16 * 64 * 8);
    bf16x8* dst = (bf16x8*)wlds;
    for (int i = tid; i < ntiles * 16 * 64; i += 512) dst[i] = src[i];
  }

  // ---- per-wave state: 2 batches ----
  const int b0 = bg * 16 + w * 2;
  float zr[2][8];
  #pragma unroll
  for (int bi = 0; bi < 2; ++bi) {
    *(float4*)&zr[bi][0] = *(const float4*)(hidden + (size_t)(b0 + bi) * E_ + l * 8);
    *(float4*)&zr[bi][4] = *(const float4*)(hidden + (size_t)(b0 + bi) * E_ + l * 8 + 4);
  }

  // ---- x pipeline: direct emb gather, one step ahead ----
  const int sq0 = b0 * T_, sq1 = (b0 + 1) * T_;
  int ian = seq[sq0], ibn = seq[sq1];
  float4 ea0 = *(const float4*)(emb + (size_t)ian * E_ + l * 8);
  float4 ea1 = *(const float4*)(emb + (size_t)ian * E_ + l * 8 + 4);
  float4 eb0 = *(const float4*)(emb + (size_t)ibn * E_ + l * 8);
  float4 eb1 = *(const float4*)(emb + (size_t)ibn * E_ + l * 8 + 4);
  ian = seq[sq0 + 1]; ibn = seq[sq1 + 1];

  unsigned* const flagline = flags + bg * 32;           // 16 u32 in one 128B line
  __syncthreads();                                      // consts staged

  #pragma unroll 1
  for (int t = 0; t < T_; ++t) {
    const int p = t & 1;
    // ---- z += x_t; stage z fragments ----
    {
      float xa[8] = {ea0.x, ea0.y, ea0.z, ea0.w, ea1.x, ea1.y, ea1.z, ea1.w};
      float xb[8] = {eb0.x, eb0.y, eb0.z, eb0.w, eb1.x, eb1.y, eb1.z, eb1.w};
      short ta[8], tb[8];
      #pragma unroll
      for (int j = 0; j < 8; ++j) {
        zr[0][j] += xa[j] * SQRTE; ta[j] = f2bf(zr[0][j]);
        zr[1][j] += xb[j] * SQRTE; tb[j] = f2bf(zr[1][j]);
      }
      const int ks = l >> 2;
      const int ua = ((l & 3) << 4) | (w * 2);
      const int ub = ua | 1;
      *(bf16x8*)&zfs[((ks << 6) + (ua ^ (ks & 7))) * 8] = *(const bf16x8*)ta;
      *(bf16x8*)&zfs[((ks << 6) + (ub ^ (ks & 7))) * 8] = *(const bf16x8*)tb;
    }
    // ---- issue next x loads (hidden under the whole step) ----
    if (t + 1 < T_) {
      ea0 = *(const float4*)(emb + (size_t)ian * E_ + l * 8);
      ea1 = *(const float4*)(emb + (size_t)ian * E_ + l * 8 + 4);
      eb0 = *(const float4*)(emb + (size_t)ibn * E_ + l * 8);
      eb1 = *(const float4*)(emb + (size_t)ibn * E_ + l * 8 + 4);
      if (t + 2 < T_) { ian = seq[sq0 + t + 2]; ibn = seq[sq1 + t + 2]; }
    }
    __syncthreads();                                    // bar1: zfs ready

    // ---- phase A: one MFMA tile per wave (waves 0..ntiles-1) ----
    if (w < ntiles) {
      const int lt = w;
      f32x4 acc = {0.f, 0.f, 0.f, 0.f};
      #pragma unroll
      for (int ks = 0; ks < 16; ++ks) {
        bf16x8 wf = *(const bf16x8*)&wlds[((lt * 16 + ks) * 64 + l) * 8];
        bf16x8 zb = *(const bf16x8*)&zfs[((ks << 6) + (l ^ (ks & 7))) * 8];
        acc = __builtin_amdgcn_mfma_f32_16x16x32_bf16(wf, zb, acc, 0, 0, 0);
      }
      const int gt = cg * 4 + lt;
      bf16x4 o;
      #pragma unroll
      for (int r = 0; r < 4; ++r) o[r] = f2bf(acc[r]);
      astore4v(Yx + (((size_t)(p * NBG + bg) * 16) + (l & 15)) * YSTR
                  + gt * 16 + ((l >> 4) << 2), o);
      asm volatile("s_waitcnt vmcnt(0)" ::: "memory");  // Y ACKed at LLC
    }
    __syncthreads();                                    // bar2: all Y stores drained

    if (tid == 0)
      __hip_atomic_store(&flagline[cg], (unsigned)(t + 1),
                         __ATOMIC_RELAXED, __HIP_MEMORY_SCOPE_AGENT);
    if (w == 0) {                                       // only wave 0 polls
      const unsigned rnd = (unsigned)(t + 1);
      const unsigned* fp = flagline + (l & 15);
      while (__hip_atomic_load(fp, __ATOMIC_RELAXED, __HIP_MEMORY_SCOPE_AGENT) < rnd)
        __builtin_amdgcn_s_sleep(1);
      asm volatile("" ::: "memory");
    }
    __syncthreads();                                    // bar3: release all waves

    // ---- phase B: 2 batches interleaved ----
    {
      const short* Yb  = Yx + ((size_t)(p * NBG + bg) * 16) * YSTR;
      const short* Yr0 = Yb + (size_t)(w * 2) * YSTR;
      const short* Yr1 = Yb + (size_t)(w * 2 + 1) * YSTR;
      bf16x8 wv0 = aload8v(Yr0 + l * 8),       wv1 = aload8v(Yr1 + l * 8);
      bf16x8 vv0 = aload8v(Yr0 + 512 + l * 8), vv1 = aload8v(Yr1 + 512 + l * 8);
      bf16x8 ma0 = aload8v(Yr0 + 1024),        ma1 = aload8v(Yr1 + 1024);
      bf16x8 mb0 = aload8v(Yr0 + 1032),        mb1 = aload8v(Yr1 + 1032);

      float cw[8];
      *(float4*)&cw[0] = *(const float4*)&cl[l * 8];
      *(float4*)&cw[4] = *(const float4*)&cl[l * 8 + 4];
      float p0 = 0.f, p1 = 0.f;
      #pragma unroll
      for (int j = 0; j < 8; ++j) {
        p0 += (bf2f(wv0[j]) + cw[j]) * zr[0][j];
        p1 += (bf2f(wv1[j]) + cw[j]) * zr[1][j];
      }
      const float r0 = wredsum(p0);
      const float r1 = wredsum(p1);

      float a0[17], a1[17];
      a0[0] = (r0 + lbl[16]) * SCALE;
      a1[0] = (r1 + lbl[16]) * SCALE;
      #pragma unroll
      for (int m = 0; m < 8; ++m) {
        a0[m + 1] = (bf2f(ma0[m]) + lbl[m]) * SCALE;
        a0[m + 9] = (bf2f(mb0[m]) + lbl[m + 8]) * SCALE;
        a1[m + 1] = (bf2f(ma1[m]) + lbl[m]) * SCALE;
        a1[m + 9] = (bf2f(mb1[m]) + lbl[m + 8]) * SCALE;
      }
      float mx0 = a0[0], mx1 = a1[0];
      #pragma unroll
      for (int n = 1; n < 17; ++n) { mx0 = fmaxf(mx0, a0[n]); mx1 = fmaxf(mx1, a1[n]); }
      float d0 = 0.f, d1 = 0.f;
      #pragma unroll
      for (int n = 0; n < 17; ++n) {
        a0[n] = __expf(a0[n] - mx0); d0 += a0[n];
        a1[n] = __expf(a1[n] - mx1); d1 += a1[n];
      }
      const float rd0 = __fdividef(1.f, d0);
      const float rd1 = __fdividef(1.f, d1);

      float bw[8];
      *(float4*)&bw[0] = *(const float4*)&bvl[l * 8];
      *(float4*)&bw[4] = *(const float4*)&bvl[l * 8 + 4];
      float u0[8], u1[8];
      #pragma unroll
      for (int j = 0; j < 8; ++j) {
        u0[j] = a0[0] * (bf2f(vv0[j]) + bw[j]);
        u1[j] = a1[0] * (bf2f(vv1[j]) + bw[j]);
      }
      #pragma unroll
      for (int m = 0; m < 16; ++m) {
        const bf16x8 vm = *(const bf16x8*)&vml[m * E_ + l * 8];
        #pragma unroll
        for (int j = 0; j < 8; ++j) {
          const float f = bf2f(vm[j]);
          u0[j] += a0[m + 1] * f;
          u1[j] += a1[m + 1] * f;
        }
      }
      #pragma unroll
      for (int j = 0; j < 8; ++j) {
        u0[j] = zr[0][j] + u0[j] * rd0;
        u1[j] = zr[1][j] + u1[j] * rd1;
      }

      float s10 = 0.f, s20 = 0.f, s11 = 0.f, s21 = 0.f;
      #pragma unroll
      for (int j = 0; j < 8; ++j) {
        s10 += u0[j]; s20 += u0[j] * u0[j];
        s11 += u1[j]; s21 += u1[j] * u1[j];
      }
      s10 = wredsum(s10); s20 = wredsum(s20);
      s11 = wredsum(s11); s21 = wredsum(s21);
      const float mean0 = s10 * (1.f / 512.f);
      const float mean1 = s11 * (1.f / 512.f);
      const float rstd0 = rsqrtf(s20 * (1.f / 512.f) - mean0 * mean0 + 1e-6f);
      const float rstd1 = rsqrtf(s21 * (1.f / 512.f) - mean1 * mean1 + 1e-6f);

      float gw[8], bb[8];
      *(float4*)&gw[0] = *(const float4*)&gl[l * 8];
      *(float4*)&gw[4] = *(const float4*)&gl[l * 8 + 4];
      *(float4*)&bb[0] = *(const float4*)&bl[l * 8];
      *(float4*)&bb[4] = *(const float4*)&bl[l * 8 + 4];
      #pragma unroll
      for (int j = 0; j < 8; ++j) {
        zr[0][j] = (u0[j] - mean0) * rstd0 * gw[j] + bb[j];
        zr[1][j] = (u1[j] - mean1) * rstd1 * gw[j] + bb[j];
      }
    }
  }

  if (cg == 0) {
    #pragma unroll
    for (int bi = 0; bi < 2; ++bi) {
      *(float4*)(zout + (size_t)(b0 + bi) * E_ + l * 8)     = *(float4*)&zr[bi][0];
      *(float4*)(zout + (size_t)(b0 + bi) * E_ + l * 8 + 4) = *(float4*)&zr[bi][4];
    }
  }
}

// ---------------- K8: logits = z @ vocab_W + vocab_b (bf16 MFMA) -----------
#define K2_SMEM (128 * ZSTR * 2)

__global__ __launch_bounds__(512, 2) void k_logits(
    const float* __restrict__ z, const float* __restrict__ W,
    const float* __restrict__ bia, float* __restrict__ out)
{
  extern __shared__ short zl[];                 // [128][ZSTR] bf16
  const int tid = threadIdx.x;
  const int btile = blockIdx.x & 1;
  const int vt = blockIdx.x >> 1;
  for (int i = tid; i < 128 * 128; i += 512) {
    int row = i >> 7, c4 = (i & 127) << 2;
    float4 zv = *(const float4*)(z + (size_t)(btile * 128 + row) * E_ + c4);
    short* d = zl + row * ZSTR + c4;
    d[0] = f2bf(zv.x); d[1] = f2bf(zv.y); d[2] = f2bf(zv.z); d[3] = f2bf(zv.w);
  }
  __syncthreads();
  const int lane = tid & 63, w = tid >> 6;
  const int vc = vt * 128 + w * 16 + (lane & 15);
  const int kq = (lane >> 4) * 8;
  f32x4 acc[8];
  #pragma unroll
  for (int rt = 0; rt < 8; ++rt) acc[rt] = (f32x4){0.f, 0.f, 0.f, 0.f};
  for (int ks = 0; ks < 16; ++ks) {
    bf16x8 bf;
    #pragma unroll
    for (int j = 0; j < 8; ++j)
      bf[j] = f2bf(W[(size_t)(ks * 32 + kq + j) * V_ + vc]);
    #pragma unroll
    for (int rt = 0; rt < 8; ++rt) {
      bf16x8 a = *(const bf16x8*)&zl[(rt * 16 + (lane & 15)) * ZSTR + ks * 32 + kq];
      acc[rt] = __builtin_amdgcn_mfma_f32_16x16x32_bf16(a, bf, acc[rt], 0, 0, 0);
    }
  }
  const float bbv = bia[vc];
  #pragma unroll
  for (int rt = 0; rt < 8; ++rt)
    #pragma unroll
    for (int r = 0; r < 4; ++r)
      out[(size_t)(btile * 128 + rt * 16 + (lane >> 4) * 4 + r) * V_ + vc] = acc[rt][r] + bbv;
}

// ---------------- K9: in-place log_softmax over vocab ----------------------
__global__ void k_logsoftmax(float* __restrict__ y)
{
  float* L = y + (size_t)blockIdx.x * V_;
  float m = -3.402823466e+38f, s = 0.f;
  for (int i = threadIdx.x; i < V_; i += 256) {
    float l = L[i];
    if (l > m) { s = s * __expf(m - l) + 1.f; m = l; }
    else       { s += __expf(l - m); }
  }
  #pragma unroll
  for (int k = 1; k < 64; k <<= 1) {
    float m2 = __shfl_xor(m, k, 64);
    float s2 = __shfl_xor(s, k, 64);
    float M = fmaxf(m, m2);
    s = s * __expf(m - M) + s2 * __expf(m2 - M);
    m = M;
  }
  __shared__ float ms[4], ss[4];
  if ((threadIdx.x & 63) == 0) { ms[threadIdx.x >> 6] = m; ss[threadIdx.x >> 6] = s; }
  __syncthreads();
  float M = fmaxf(fmaxf(ms[0], ms[1]), fmaxf(ms[2], ms[3]));
  float S = ss[0] * __expf(ms[0] - M) + ss[1] * __expf(ms[1] - M) +
            ss[2] * __expf(ms[2] - M) + ss[3] * __expf(ms[3] - M);
  const float lse = M + logf(S);
  for (int i = threadIdx.x; i < V_; i += 256) L[i] -= lse;
}

#define SCAN_SMEM 123008

extern "C" void kernel_launch(void* const* d_in, const int* in_sizes, int n_in,
                              void* d_out, int out_size, void* d_ws, size_t ws_size,
                              hipStream_t stream) {
  const float* hidden = (const float*)d_in[0];
  const int*   seq    = (const int*)  d_in[1];
  const float* emb    = (const float*)d_in[2];
  const float* Wq     = (const float*)d_in[3];
  const float* bq     = (const float*)d_in[4];
  const float* Wk     = (const float*)d_in[5];
  const float* bk     = (const float*)d_in[6];
  const float* Wv     = (const float*)d_in[7];
  const float* bv     = (const float*)d_in[8];
  const float* mover  = (const float*)d_in[9];
  const float* gamma  = (const float*)d_in[10];
  const float* beta   = (const float*)d_in[11];
  const float* vocabW = (const float*)d_in[12];
  const float* vocabB = (const float*)d_in[13];

  float* zoutp = (float*)d_out;                 // (256,1,512)
  float* yout  = zoutp + (size_t)B_ * E_;       // (256,1,32000); scratch until k_logits

  // scratch inside yout (all overwritten by k_logits afterwards)
  short*    Wfrag = (short*)yout;               // 65*16*64*8 = 532480 bf16
  float*    A     = yout + 266240;              // 512*512
  float*    Wqk   = A + 262144;                 // 512*16
  float*    cvec  = Wqk + 8192;                 // 512
  float*    lbp   = cvec + 512;                 // 17 (pad 32)
  float*    kmvmS = lbp + 32;                   // 2*16*512
  short*    Yx    = (short*)(kmvmS + 16384);    // [2][16][16][1056] bf16 = 540672
  unsigned* flags = (unsigned*)(Yx + 540672);   // 16 bg x 32 u32 (one 128B line each)

  hipMemsetAsync(flags, 0, 16 * 32 * 4, stream);
  hipLaunchKernelGGL(k_movers, dim3(32), dim3(256), 0, stream, Wk, bk, Wv, bv, mover, kmvmS);
  hipLaunchKernelGGL(k_gemmA,  dim3(1024), dim3(64), 0, stream, Wq, Wk, A);
  hipLaunchKernelGGL(k_wqk,    dim3(512), dim3(64), 0, stream, Wq, kmvmS, Wqk);
  hipLaunchKernelGGL(k_cvec,   dim3(8), dim3(64), 0, stream, Wq, Wk, bq, bk, cvec);
  hipLaunchKernelGGL(k_lb,     dim3(1), dim3(64), 0, stream, bq, bk, kmvmS, lbp);
  hipLaunchKernelGGL(k_pack,   dim3(NT * 16), dim3(64), 0, stream, A, Wv, Wqk, Wfrag);

  hipFuncSetAttribute((const void*)k_scan5, hipFuncAttributeMaxDynamicSharedMemorySize, SCAN_SMEM);
  void* args[] = {(void*)&hidden, (void*)&seq, (void*)&emb,
                  (void*)&gamma, (void*)&beta, (void*)&bv,
                  (void*)&kmvmS, (void*)&cvec, (void*)&lbp, (void*)&Wfrag,
                  (void*)&Yx, (void*)&flags, (void*)&zoutp};
  hipLaunchCooperativeKernel((const void*)k_scan5, dim3(NCG * NBG), dim3(512),
                             args, SCAN_SMEM, stream);

  hipFuncSetAttribute((const void*)k_logits, hipFuncAttributeMaxDynamicSharedMemorySize, K2_SMEM);
  hipLaunchKernelGGL(k_logits, dim3(500), dim3(512), K2_SMEM, stream, zoutp, vocabW, vocabB, yout);
  hipLaunchKernelGGL(k_logsoftmax, dim3(256), dim3(256), 0, stream, yout);
}

// Round 6
// 1297.641 us; speedup vs baseline: 7.5038x; 1.1722x over previous
//
#include <hip/hip_runtime.h>

#define B_ 256
#define T_ 256
#define E_ 512
#define V_ 32000
#define NMOV 16
#define NT 65              // column tiles: A(32) | Wv(32) | Wqk(1)
#define NCG 16             // column groups
#define NBG 16             // batch groups
#define YSTR 1056          // Y exchange row stride (bf16 units)
#define ZSTR 520           // k_logits LDS stride

#define SQRTE 22.62741699796952f
#define SCALE 0.04419417382415922f   // 1/sqrt(512)

typedef __attribute__((ext_vector_type(8))) short bf16x8;
typedef __attribute__((ext_vector_type(4))) short bf16x4;
typedef __attribute__((ext_vector_type(4))) float f32x4;
typedef unsigned long long u64;

__device__ __forceinline__ short f2bf(float f) {
  unsigned u = __float_as_uint(f);
  u += 0x7fffu + ((u >> 16) & 1u);          // RNE
  return (short)(u >> 16);
}
__device__ __forceinline__ float bf2f(short s) {
  return __uint_as_float(((unsigned)(unsigned short)s) << 16);
}

// full-wave64 sum -> uniform scalar (DPP butterfly + readlane)
__device__ __forceinline__ float wredsum(float v) {
  int x;
  x = __builtin_amdgcn_update_dpp(0, __float_as_int(v), 0xB1, 0xF, 0xF, true);
  v += __int_as_float(x);
  x = __builtin_amdgcn_update_dpp(0, __float_as_int(v), 0x4E, 0xF, 0xF, true);
  v += __int_as_float(x);
  x = __builtin_amdgcn_update_dpp(0, __float_as_int(v), 0x141, 0xF, 0xF, true);
  v += __int_as_float(x);
  x = __builtin_amdgcn_update_dpp(0, __float_as_int(v), 0x140, 0xF, 0xF, true);
  v += __int_as_float(x);
  x = __builtin_amdgcn_update_dpp(0, __float_as_int(v), 0x142, 0xF, 0xF, true);
  v += __int_as_float(x);
  x = __builtin_amdgcn_update_dpp(0, __float_as_int(v), 0x143, 0xF, 0xF, true);
  v += __int_as_float(x);
  return __int_as_float(__builtin_amdgcn_readlane(__float_as_int(v), 63));
}
// row-of-16 butterfly reductions (every lane gets its row's result)
__device__ __forceinline__ float rowmax16(float v) {
  int x;
  x = __builtin_amdgcn_update_dpp(0, __float_as_int(v), 0xB1, 0xF, 0xF, true);
  v = fmaxf(v, __int_as_float(x));
  x = __builtin_amdgcn_update_dpp(0, __float_as_int(v), 0x4E, 0xF, 0xF, true);
  v = fmaxf(v, __int_as_float(x));
  x = __builtin_amdgcn_update_dpp(0, __float_as_int(v), 0x141, 0xF, 0xF, true);
  v = fmaxf(v, __int_as_float(x));
  x = __builtin_amdgcn_update_dpp(0, __float_as_int(v), 0x140, 0xF, 0xF, true);
  v = fmaxf(v, __int_as_float(x));
  return v;
}
__device__ __forceinline__ float rowsum16(float v) {
  int x;
  x = __builtin_amdgcn_update_dpp(0, __float_as_int(v), 0xB1, 0xF, 0xF, true);
  v += __int_as_float(x);
  x = __builtin_amdgcn_update_dpp(0, __float_as_int(v), 0x4E, 0xF, 0xF, true);
  v += __int_as_float(x);
  x = __builtin_amdgcn_update_dpp(0, __float_as_int(v), 0x141, 0xF, 0xF, true);
  v += __int_as_float(x);
  x = __builtin_amdgcn_update_dpp(0, __float_as_int(v), 0x140, 0xF, 0xF, true);
  v += __int_as_float(x);
  return v;
}
__device__ __forceinline__ float rdlane(float v, int lane) {
  return __int_as_float(__builtin_amdgcn_readlane(__float_as_int(v), lane));
}

// relaxed agent-scope (coherence-point) helpers — no cache maintenance
__device__ __forceinline__ bf16x8 aload8v(const short* p) {
  union { u64 u[2]; bf16x8 v; } c;
  c.u[0] = __hip_atomic_load((const u64*)p,       __ATOMIC_RELAXED, __HIP_MEMORY_SCOPE_AGENT);
  c.u[1] = __hip_atomic_load((const u64*)(p + 4), __ATOMIC_RELAXED, __HIP_MEMORY_SCOPE_AGENT);
  return c.v;
}
__device__ __forceinline__ void astore4v(short* p, bf16x4 v) {
  union { bf16x4 v; u64 u; } c; c.v = v;
  __hip_atomic_store((u64*)p, c.u, __ATOMIC_RELAXED, __HIP_MEMORY_SCOPE_AGENT);
}

// ---------------- K1: mover K/V: Km = mover@Wk + bk, Vm = mover@Wv + bv ----
__global__ void k_movers(const float* __restrict__ Wk, const float* __restrict__ bk,
                         const float* __restrict__ Wv, const float* __restrict__ bv,
                         const float* __restrict__ mover, float* __restrict__ kmvm)
{
  const int m = blockIdx.x & 15;
  const int s = blockIdx.x >> 4;              // 0 -> K, 1 -> V
  const float* W  = s ? Wv : Wk;
  const float* bb = s ? bv : bk;
  const int c = threadIdx.x * 2;
  float a0 = bb[c], a1 = bb[c + 1];
  for (int r = 0; r < E_; ++r) {
    float mv = mover[m * E_ + r];
    float2 wv = *(const float2*)(W + (size_t)r * E_ + c);
    a0 += mv * wv.x; a1 += mv * wv.y;
  }
  kmvm[(s * NMOV + m) * E_ + c]     = a0;
  kmvm[(s * NMOV + m) * E_ + c + 1] = a1;
}

// ---------------- K2: A = Wq @ Wk^T (bf16 MFMA, f32 out) -------------------
__global__ void k_gemmA(const float* __restrict__ Wq, const float* __restrict__ Wk,
                        float* __restrict__ A)
{
  const int ti = blockIdx.x >> 5, tj = blockIdx.x & 31;
  const int l = threadIdx.x, r16 = l & 15, kq = (l >> 4) * 8;
  f32x4 acc = {0.f, 0.f, 0.f, 0.f};
  for (int ks = 0; ks < 16; ++ks) {
    const float* ap = Wq + (size_t)(ti * 16 + r16) * E_ + ks * 32 + kq;
    const float* bp = Wk + (size_t)(tj * 16 + r16) * E_ + ks * 32 + kq;
    bf16x8 a, b;
    #pragma unroll
    for (int j = 0; j < 8; ++j) { a[j] = f2bf(ap[j]); b[j] = f2bf(bp[j]); }
    acc = __builtin_amdgcn_mfma_f32_16x16x32_bf16(a, b, acc, 0, 0, 0);
  }
  #pragma unroll
  for (int r = 0; r < 4; ++r)
    A[(size_t)(ti * 16 + (l >> 4) * 4 + r) * E_ + tj * 16 + r16] = acc[r];
}

// ---------------- K3: Wqk[i][m] = sum_j Wq[i][j] * Km[m][j] ----------------
__global__ void k_wqk(const float* __restrict__ Wq, const float* __restrict__ kmvm,
                      float* __restrict__ Wqk)
{
  const int i = blockIdx.x;
  const int l = threadIdx.x, m = l & 15, sl = l >> 4;
  float p = 0.f;
  for (int j = sl * 128; j < sl * 128 + 128; ++j)
    p += Wq[(size_t)i * E_ + j] * kmvm[(size_t)m * E_ + j];
  p += __shfl_xor(p, 16, 64);
  p += __shfl_xor(p, 32, 64);
  if (l < 16) Wqk[i * 16 + m] = p;
}

// ---------------- K4: cvec[i] = Wq[i]·bk + Wk[i]·bq ------------------------
__global__ void k_cvec(const float* __restrict__ Wq, const float* __restrict__ Wk,
                       const float* __restrict__ bq, const float* __restrict__ bk,
                       float* __restrict__ cvec)
{
  const int i = blockIdx.x * 64 + threadIdx.x;
  float s = 0.f;
  for (int j = 0; j < E_; ++j)
    s += Wq[(size_t)i * E_ + j] * bk[j] + Wk[(size_t)i * E_ + j] * bq[j];
  cvec[i] = s;
}

// ---------------- K5: lb[m] = bq·Km[m] (m<16), lb[16] = bq·bk --------------
__global__ void k_lb(const float* __restrict__ bq, const float* __restrict__ bk,
                     const float* __restrict__ kmvm, float* __restrict__ lb)
{
  const int l = threadIdx.x;
  if (l < 16) {
    float s = 0.f;
    for (int j = 0; j < E_; ++j) s += bq[j] * kmvm[(size_t)l * E_ + j];
    lb[l] = s;
  } else if (l == 16) {
    float s = 0.f;
    for (int j = 0; j < E_; ++j) s += bq[j] * bk[j];
    lb[16] = s;
  }
}

// ---------------- K6: pack Wcat = [A | Wv | Wqk] into MFMA fragment order --
__global__ void k_pack(const float* __restrict__ A, const float* __restrict__ Wv,
                       const float* __restrict__ Wqk, short* __restrict__ Wfrag)
{
  const int blk = blockIdx.x;          // ct*16 + ks
  const int ct = blk >> 4, ks = blk & 15;
  const int l = threadIdx.x;
  const int c = ct * 16 + (l & 15);
  const int r0 = ks * 32 + (l >> 4) * 8;
  short v[8];
  #pragma unroll
  for (int j = 0; j < 8; ++j) {
    const int r = r0 + j;
    float x;
    if (c < 512)       x = A[(size_t)r * E_ + c];
    else if (c < 1024) x = Wv[(size_t)r * E_ + (c - 512)];
    else               x = Wqk[r * 16 + (c - 1024)];
    v[j] = f2bf(x);
  }
  *(bf16x8*)(Wfrag + ((size_t)blk * 64 + l) * 8) = *(const bf16x8*)v;
}

// ---------------- K7: scan with MFMA-PV + lane-parallel softmax ------------
// 256 WGs = 16 cg x 16 bg, 512 threads (8 waves), 1 WG/CU.
// Per step: stage z -> bar1 -> phase A (waves 0..ntiles-1: 16 MFMA + Y store
// + vmcnt ack) -> bar2 -> tid0 flag -> all waves poll 15 remote flags ->
// Y reads + dot + lane-softmax (lane&15 = mover, lane half = batch) -> attf
// -> barB1 -> PV via 4x mfma_16x16x32 (att @ Vm) -> umov -> barB2 ->
// owner combine + LayerNorm.
__global__ __launch_bounds__(512, 2) void k_scan6(
    const float* __restrict__ hidden, const int* __restrict__ seq,
    const float* __restrict__ emb,
    const float* __restrict__ gamma, const float* __restrict__ beta,
    const float* __restrict__ bv,
    const float* __restrict__ kmvm, const float* __restrict__ cvec,
    const float* __restrict__ lb, const short* __restrict__ Wfrag,
    short* __restrict__ Yx, unsigned* __restrict__ flags,
    float* __restrict__ zout)
{
  extern __shared__ char smem[];
  short* wlds    = (short*)smem;                  // 81920 B: <=5 weight tiles
  short* zfs     = (short*)(smem + 81920);        // 16384 B: z B-fragments
  short* vmfragT = (short*)(smem + 98304);        // 16384 B: Vm^T A-frags [32][32][8]
  float* umov    = (float*)(smem + 114688);       // 33280 B: [16][520] f32
  short* attf    = (short*)(smem + 147968);       // 1280 B: [16][40] bf16

  const int tid = threadIdx.x, l = tid & 63, w = tid >> 6;
  const int cg = blockIdx.x >> 4;
  const int bg = blockIdx.x & 15;
  const int ntiles = (cg == 15) ? 5 : 4;
  const int lm = l & 15;

  // ---- stage constants ----
  // Vm^T A-fragments: lane ln<32 of tile: Vm[(ln>>4)*8+j][tile*16+(ln&15)]
  for (int i = tid; i < 32 * 32; i += 512) {
    const int tile = i >> 5, ln = i & 31;
    const int m0 = (ln >> 4) * 8, c = tile * 16 + (ln & 15);
    short tmp[8];
    #pragma unroll
    for (int j = 0; j < 8; ++j)
      tmp[j] = f2bf(kmvm[NMOV * E_ + (size_t)(m0 + j) * E_ + c]);
    *(bf16x8*)&vmfragT[((size_t)tile * 32 + ln) * 8] = *(const bf16x8*)tmp;
  }
  for (int i = tid; i < 16 * 40; i += 512) attf[i] = 0;   // cols 16..39 stay 0
  {
    const bf16x8* src = (const bf16x8*)(Wfrag + (size_t)(cg * 4) * 16 * 64 * 8);
    bf16x8* dst = (bf16x8*)wlds;
    for (int i = tid; i < ntiles * 16 * 64; i += 512) dst[i] = src[i];
  }

  // ---- time-invariant per-lane vectors in registers ----
  float cw[8], bw[8], gw[8], bb[8];
  *(float4*)&cw[0] = *(const float4*)(cvec  + l * 8);
  *(float4*)&cw[4] = *(const float4*)(cvec  + l * 8 + 4);
  *(float4*)&bw[0] = *(const float4*)(bv    + l * 8);
  *(float4*)&bw[4] = *(const float4*)(bv    + l * 8 + 4);
  *(float4*)&gw[0] = *(const float4*)(gamma + l * 8);
  *(float4*)&gw[4] = *(const float4*)(gamma + l * 8 + 4);
  *(float4*)&bb[0] = *(const float4*)(beta  + l * 8);
  *(float4*)&bb[4] = *(const float4*)(beta  + l * 8 + 4);
  const float lbw  = lb[lm];          // mover bias for this lane's mover
  const float lb16 = lb[16];

  // ---- per-wave state: 2 batches ----
  const int b0 = bg * 16 + w * 2;
  float zr[2][8];
  #pragma unroll
  for (int bi = 0; bi < 2; ++bi) {
    *(float4*)&zr[bi][0] = *(const float4*)(hidden + (size_t)(b0 + bi) * E_ + l * 8);
    *(float4*)&zr[bi][4] = *(const float4*)(hidden + (size_t)(b0 + bi) * E_ + l * 8 + 4);
  }

  // ---- x pipeline: direct emb gather, one step ahead ----
  const int sq0 = b0 * T_, sq1 = (b0 + 1) * T_;
  int ian = seq[sq0], ibn = seq[sq1];
  float4 ea0 = *(const float4*)(emb + (size_t)ian * E_ + l * 8);
  float4 ea1 = *(const float4*)(emb + (size_t)ian * E_ + l * 8 + 4);
  float4 eb0 = *(const float4*)(emb + (size_t)ibn * E_ + l * 8);
  float4 eb1 = *(const float4*)(emb + (size_t)ibn * E_ + l * 8 + 4);
  ian = seq[sq0 + 1]; ibn = seq[sq1 + 1];

  unsigned* const flagline = flags + bg * 32;     // 16 u32 in one 128B line
  __syncthreads();                                // consts staged

  #pragma unroll 1
  for (int t = 0; t < T_; ++t) {
    const int p = t & 1;
    // ---- z += x_t; stage z fragments ----
    {
      float xa[8] = {ea0.x, ea0.y, ea0.z, ea0.w, ea1.x, ea1.y, ea1.z, ea1.w};
      float xb[8] = {eb0.x, eb0.y, eb0.z, eb0.w, eb1.x, eb1.y, eb1.z, eb1.w};
      short ta[8], tb[8];
      #pragma unroll
      for (int j = 0; j < 8; ++j) {
        zr[0][j] += xa[j] * SQRTE; ta[j] = f2bf(zr[0][j]);
        zr[1][j] += xb[j] * SQRTE; tb[j] = f2bf(zr[1][j]);
      }
      const int ks = l >> 2;
      const int ua = ((l & 3) << 4) | (w * 2);
      const int ub = ua | 1;
      *(bf16x8*)&zfs[((ks << 6) + (ua ^ (ks & 7))) * 8] = *(const bf16x8*)ta;
      *(bf16x8*)&zfs[((ks << 6) + (ub ^ (ks & 7))) * 8] = *(const bf16x8*)tb;
    }
    if (t + 1 < T_) {
      ea0 = *(const float4*)(emb + (size_t)ian * E_ + l * 8);
      ea1 = *(const float4*)(emb + (size_t)ian * E_ + l * 8 + 4);
      eb0 = *(const float4*)(emb + (size_t)ibn * E_ + l * 8);
      eb1 = *(const float4*)(emb + (size_t)ibn * E_ + l * 8 + 4);
      if (t + 2 < T_) { ian = seq[sq0 + t + 2]; ibn = seq[sq1 + t + 2]; }
    }
    __syncthreads();                              // bar1: zfs ready

    // ---- phase A: one MFMA tile per wave ----
    if (w < ntiles) {
      f32x4 acc = {0.f, 0.f, 0.f, 0.f};
      #pragma unroll
      for (int ks = 0; ks < 16; ++ks) {
        bf16x8 wf = *(const bf16x8*)&wlds[((w * 16 + ks) * 64 + l) * 8];
        bf16x8 zb = *(const bf16x8*)&zfs[((ks << 6) + (l ^ (ks & 7))) * 8];
        acc = __builtin_amdgcn_mfma_f32_16x16x32_bf16(wf, zb, acc, 0, 0, 0);
      }
      const int gt = cg * 4 + w;
      bf16x4 o;
      #pragma unroll
      for (int r = 0; r < 4; ++r) o[r] = f2bf(acc[r]);
      astore4v(Yx + (((size_t)(p * NBG + bg) * 16) + lm) * YSTR
                  + gt * 16 + ((l >> 4) << 2), o);
      asm volatile("s_waitcnt vmcnt(0)" ::: "memory");
    }
    __syncthreads();                              // bar2: all Y stores ACKed

    if (tid == 0)
      __hip_atomic_store(&flagline[cg], (unsigned)(t + 1),
                         __ATOMIC_RELAXED, __HIP_MEMORY_SCOPE_AGENT);
    // ---- every wave polls the 15 remote flags (skip own cg) ----
    {
      const unsigned rnd = (unsigned)(t + 1);
      for (;;) {
        unsigned f = __hip_atomic_load(&flagline[lm], __ATOMIC_RELAXED,
                                       __HIP_MEMORY_SCOPE_AGENT);
        if (__all(lm == cg || f >= rnd)) break;
        __builtin_amdgcn_s_sleep(1);
      }
      asm volatile("" ::: "memory");
    }

    // ---- phase B ----
    const short* Yb  = Yx + ((size_t)(p * NBG + bg) * 16) * YSTR;
    const short* Yr0 = Yb + (size_t)(w * 2) * YSTR;
    const short* Yr1 = Yb + (size_t)(w * 2 + 1) * YSTR;
    bf16x8 wv0 = aload8v(Yr0 + l * 8),       wv1 = aload8v(Yr1 + l * 8);
    bf16x8 vv0 = aload8v(Yr0 + 512 + l * 8), vv1 = aload8v(Yr1 + 512 + l * 8);
    // per-lane mover logit (batch by lane half)
    const short* Yrh = (l < 32) ? Yr0 : Yr1;
    short mlr = (short)__hip_atomic_load((const short*)(Yrh + 1024 + lm),
                                         __ATOMIC_RELAXED, __HIP_MEMORY_SCOPE_AGENT);

    // q.k0 dots (full-wave reductions)
    float p0 = 0.f, p1 = 0.f;
    #pragma unroll
    for (int j = 0; j < 8; ++j) {
      p0 += (bf2f(wv0[j]) + cw[j]) * zr[0][j];
      p1 += (bf2f(wv1[j]) + cw[j]) * zr[1][j];
    }
    const float dl0 = (wredsum(p0) + lb16) * SCALE;
    const float dl1 = (wredsum(p1) + lb16) * SCALE;

    // lane-parallel softmax over 16 movers + scalar k0 term
    const float dl   = (l < 32) ? dl0 : dl1;
    const float lgt  = (bf2f(mlr) + lbw) * SCALE;
    const float mx   = fmaxf(rowmax16(lgt), dl);
    const float e    = __expf(lgt - mx);
    const float a0v  = __expf(dl - mx);
    const float den  = rowsum16(e) + a0v;
    if ((l & 16) == 0)
      attf[(w * 2 + (l >> 5)) * 40 + lm] = f2bf(e);

    const float a00 = rdlane(a0v, 0),  a01 = rdlane(a0v, 32);
    const float rd0 = __fdividef(1.f, rdlane(den, 0));
    const float rd1 = __fdividef(1.f, rdlane(den, 32));

    __syncthreads();                              // barB1: attf ready

    // PV: 4 col-tiles per wave, D[row=ucol][col=batch]
    #pragma unroll
    for (int tt = 0; tt < 4; ++tt) {
      const int tile = w * 4 + tt;
      bf16x8 af = {0, 0, 0, 0, 0, 0, 0, 0};
      if (l < 32) af = *(const bf16x8*)&vmfragT[((size_t)tile * 32 + l) * 8];
      bf16x8 bf = *(const bf16x8*)&attf[lm * 40 + (l >> 4) * 8];
      f32x4 z4 = {0.f, 0.f, 0.f, 0.f};
      z4 = __builtin_amdgcn_mfma_f32_16x16x32_bf16(af, bf, z4, 0, 0, 0);
      *(f32x4*)&umov[(size_t)lm * 520 + tile * 16 + ((l >> 4) << 2)] = z4;
    }
    __syncthreads();                              // barB2: umov ready

    // owner combine + LayerNorm
    {
      float um0[8], um1[8], u0[8], u1[8];
      *(float4*)&um0[0] = *(const float4*)&umov[(size_t)(w * 2) * 520 + l * 8];
      *(float4*)&um0[4] = *(const float4*)&umov[(size_t)(w * 2) * 520 + l * 8 + 4];
      *(float4*)&um1[0] = *(const float4*)&umov[(size_t)(w * 2 + 1) * 520 + l * 8];
      *(float4*)&um1[4] = *(const float4*)&umov[(size_t)(w * 2 + 1) * 520 + l * 8 + 4];
      #pragma unroll
      for (int j = 0; j < 8; ++j) {
        u0[j] = zr[0][j] + (a00 * (bf2f(vv0[j]) + bw[j]) + um0[j]) * rd0;
        u1[j] = zr[1][j] + (a01 * (bf2f(vv1[j]) + bw[j]) + um1[j]) * rd1;
      }
      float s10 = 0.f, s20 = 0.f, s11 = 0.f, s21 = 0.f;
      #pragma unroll
      for (int j = 0; j < 8; ++j) {
        s10 += u0[j]; s20 += u0[j] * u0[j];
        s11 += u1[j]; s21 += u1[j] * u1[j];
      }
      s10 = wredsum(s10); s20 = wredsum(s20);
      s11 = wredsum(s11); s21 = wredsum(s21);
      const float mean0 = s10 * (1.f / 512.f);
      const float mean1 = s11 * (1.f / 512.f);
      const float rstd0 = rsqrtf(s20 * (1.f / 512.f) - mean0 * mean0 + 1e-6f);
      const float rstd1 = rsqrtf(s21 * (1.f / 512.f) - mean1 * mean1 + 1e-6f);
      #pragma unroll
      for (int j = 0; j < 8; ++j) {
        zr[0][j] = (u0[j] - mean0) * rstd0 * gw[j] + bb[j];
        zr[1][j] = (u1[j] - mean1) * rstd1 * gw[j] + bb[j];
      }
    }
  }

  if (cg == 0) {
    #pragma unroll
    for (int bi = 0; bi < 2; ++bi) {
      *(float4*)(zout + (size_t)(b0 + bi) * E_ + l * 8)     = *(float4*)&zr[bi][0];
      *(float4*)(zout + (size_t)(b0 + bi) * E_ + l * 8 + 4) = *(float4*)&zr[bi][4];
    }
  }
}

// ---------------- K8: logits = z @ vocab_W + vocab_b (bf16 MFMA) -----------
#define K2_SMEM (128 * ZSTR * 2)

__global__ __launch_bounds__(512, 2) void k_logits(
    const float* __restrict__ z, const float* __restrict__ W,
    const float* __restrict__ bia, float* __restrict__ out)
{
  extern __shared__ short zl[];                 // [128][ZSTR] bf16
  const int tid = threadIdx.x;
  const int btile = blockIdx.x & 1;
  const int vt = blockIdx.x >> 1;
  for (int i = tid; i < 128 * 128; i += 512) {
    int row = i >> 7, c4 = (i & 127) << 2;
    float4 zv = *(const float4*)(z + (size_t)(btile * 128 + row) * E_ + c4);
    short* d = zl + row * ZSTR + c4;
    d[0] = f2bf(zv.x); d[1] = f2bf(zv.y); d[2] = f2bf(zv.z); d[3] = f2bf(zv.w);
  }
  __syncthreads();
  const int lane = tid & 63, w = tid >> 6;
  const int vc = vt * 128 + w * 16 + (lane & 15);
  const int kq = (lane >> 4) * 8;
  f32x4 acc[8];
  #pragma unroll
  for (int rt = 0; rt < 8; ++rt) acc[rt] = (f32x4){0.f, 0.f, 0.f, 0.f};
  for (int ks = 0; ks < 16; ++ks) {
    bf16x8 bf;
    #pragma unroll
    for (int j = 0; j < 8; ++j)
      bf[j] = f2bf(W[(size_t)(ks * 32 + kq + j) * V_ + vc]);
    #pragma unroll
    for (int rt = 0; rt < 8; ++rt) {
      bf16x8 a = *(const bf16x8*)&zl[(rt * 16 + (lane & 15)) * ZSTR + ks * 32 + kq];
      acc[rt] = __builtin_amdgcn_mfma_f32_16x16x32_bf16(a, bf, acc[rt], 0, 0, 0);
    }
  }
  const float bbv = bia[vc];
  #pragma unroll
  for (int rt = 0; rt < 8; ++rt)
    #pragma unroll
    for (int r = 0; r < 4; ++r)
      out[(size_t)(btile * 128 + rt * 16 + (lane >> 4) * 4 + r) * V_ + vc] = acc[rt][r] + bbv;
}

// ---------------- K9: in-place log_softmax over vocab ----------------------
__global__ void k_logsoftmax(float* __restrict__ y)
{
  float* L = y + (size_t)blockIdx.x * V_;
  float m = -3.402823466e+38f, s = 0.f;
  for (int i = threadIdx.x; i < V_; i += 256) {
    float l = L[i];
    if (l > m) { s = s * __expf(m - l) + 1.f; m = l; }
    else       { s += __expf(l - m); }
  }
  #pragma unroll
  for (int k = 1; k < 64; k <<= 1) {
    float m2 = __shfl_xor(m, k, 64);
    float s2 = __shfl_xor(s, k, 64);
    float M = fmaxf(m, m2);
    s = s * __expf(m - M) + s2 * __expf(m2 - M);
    m = M;
  }
  __shared__ float ms[4], ss[4];
  if ((threadIdx.x & 63) == 0) { ms[threadIdx.x >> 6] = m; ss[threadIdx.x >> 6] = s; }
  __syncthreads();
  float M = fmaxf(fmaxf(ms[0], ms[1]), fmaxf(ms[2], ms[3]));
  float S = ss[0] * __expf(ms[0] - M) + ss[1] * __expf(ms[1] - M) +
            ss[2] * __expf(ms[2] - M) + ss[3] * __expf(ms[3] - M);
  const float lse = M + logf(S);
  for (int i = threadIdx.x; i < V_; i += 256) L[i] -= lse;
}

#define SCAN_SMEM 149248

extern "C" void kernel_launch(void* const* d_in, const int* in_sizes, int n_in,
                              void* d_out, int out_size, void* d_ws, size_t ws_size,
                              hipStream_t stream) {
  const float* hidden = (const float*)d_in[0];
  const int*   seq    = (const int*)  d_in[1];
  const float* emb    = (const float*)d_in[2];
  const float* Wq     = (const float*)d_in[3];
  const float* bq     = (const float*)d_in[4];
  const float* Wk     = (const float*)d_in[5];
  const float* bk     = (const float*)d_in[6];
  const float* Wv     = (const float*)d_in[7];
  const float* bv     = (const float*)d_in[8];
  const float* mover  = (const float*)d_in[9];
  const float* gamma  = (const float*)d_in[10];
  const float* beta   = (const float*)d_in[11];
  const float* vocabW = (const float*)d_in[12];
  const float* vocabB = (const float*)d_in[13];

  float* zoutp = (float*)d_out;                 // (256,1,512)
  float* yout  = zoutp + (size_t)B_ * E_;       // (256,1,32000); scratch until k_logits

  // scratch inside yout (all overwritten by k_logits afterwards)
  short*    Wfrag = (short*)yout;               // 65*16*64*8 = 532480 bf16
  float*    A     = yout + 266240;              // 512*512
  float*    Wqk   = A + 262144;                 // 512*16
  float*    cvec  = Wqk + 8192;                 // 512
  float*    lbp   = cvec + 512;                 // 17 (pad 32)
  float*    kmvmS = lbp + 32;                   // 2*16*512
  short*    Yx    = (short*)(kmvmS + 16384);    // [2][16][16][1056] bf16 = 540672
  unsigned* flags = (unsigned*)(Yx + 540672);   // 16 bg x 32 u32 (one 128B line each)

  hipMemsetAsync(flags, 0, 16 * 32 * 4, stream);
  hipLaunchKernelGGL(k_movers, dim3(32), dim3(256), 0, stream, Wk, bk, Wv, bv, mover, kmvmS);
  hipLaunchKernelGGL(k_gemmA,  dim3(1024), dim3(64), 0, stream, Wq, Wk, A);
  hipLaunchKernelGGL(k_wqk,    dim3(512), dim3(64), 0, stream, Wq, kmvmS, Wqk);
  hipLaunchKernelGGL(k_cvec,   dim3(8), dim3(64), 0, stream, Wq, Wk, bq, bk, cvec);
  hipLaunchKernelGGL(k_lb,     dim3(1), dim3(64), 0, stream, bq, bk, kmvmS, lbp);
  hipLaunchKernelGGL(k_pack,   dim3(NT * 16), dim3(64), 0, stream, A, Wv, Wqk, Wfrag);

  hipFuncSetAttribute((const void*)k_scan6, hipFuncAttributeMaxDynamicSharedMemorySize, SCAN_SMEM);
  void* args[] = {(void*)&hidden, (void*)&seq, (void*)&emb,
                  (void*)&gamma, (void*)&beta, (void*)&bv,
                  (void*)&kmvmS, (void*)&cvec, (void*)&lbp, (void*)&Wfrag,
                  (void*)&Yx, (void*)&flags, (void*)&zoutp};
  hipLaunchCooperativeKernel((const void*)k_scan6, dim3(NCG * NBG), dim3(512),
                             args, SCAN_SMEM, stream);

  hipFuncSetAttribute((const void*)k_logits, hipFuncAttributeMaxDynamicSharedMemorySize, K2_SMEM);
  hipLaunchKernelGGL(k_logits, dim3(500), dim3(512), K2_SMEM, stream, zoutp, vocabW, vocabB, yout);
  hipLaunchKernelGGL(k_logsoftmax, dim3(256), dim3(256), 0, stream, yout);
}